// Round 14
// baseline (464.163 us; speedup 1.0000x reference)
//
#include <hip/hip_runtime.h>
#include <hip/hip_bf16.h>

#define B_ 256
#define T_ 100
#define EMBED_ 36
#define DM_ 72
#define H_ 4
#define E_ 18
#define PATCH_ 16
#define STRIDE_ 8
#define SEQ_ 101   // T+1
#define PN_ 12
#define DFF_ 1152

#define KP 96      // K padded (72 -> 96)

// fused-kernel LDS offsets in u16 units (96-token blocks)
// z1f (post-LN1, f32 [96][76]) overlays [0 .. 14592) after phase 2 is done
#define VT2_OFF 18432   // after qk [2][4][96][24] = 18,432 u16
#define PT2_OFF 28224   // after vT  (4*2448 = 9,792 u16)
#define OL2_OFF 30528   // after Pt  (6*384 = 2,304 u16)
// o_lds [97][80] = 7,760 u16 -> total 38,288 u16 = 76,576 B

typedef __attribute__((ext_vector_type(8))) short s8v;     // 8 bf16
typedef __attribute__((ext_vector_type(4))) float f32x4;

__device__ __forceinline__ unsigned short f2b(float x) {
  __hip_bfloat16 b = __float2bfloat16(x);
  return __builtin_bit_cast(unsigned short, b);
}
// cheap round-half-up bf16 (<=1 ulp vs RTNE, finite inputs only)
__device__ __forceinline__ unsigned short f2bc(float x) {
  return (unsigned short)((__builtin_bit_cast(unsigned int, x) + 0x8000u) >> 16);
}
__device__ __forceinline__ unsigned int pk2f(float lo, float hi) {
  unsigned int ul = __builtin_bit_cast(unsigned int, lo) + 0x8000u;
  unsigned int uh = __builtin_bit_cast(unsigned int, hi) + 0x8000u;
  return __builtin_amdgcn_perm(uh, ul, 0x07060302u);
}
// bf16 fragment (8 consecutive k) from an f32 row (global or LDS).
// k0==72 returns the "one-hot" fragment {1,0,...} (bias row selector).
__device__ __forceinline__ s8v zfrag_any(const float* row, int k0) {
  if (k0 >= 72) {
    uint4 z = {0u, 0u, 0u, 0u};
    if (k0 == 72) z.x = 0x3F80u;
    return __builtin_bit_cast(s8v, z);
  }
  float4 f0 = *(const float4*)(row + k0);
  float4 f1 = *(const float4*)(row + k0 + 4);
  uint4 u;
  u.x = pk2f(f0.x, f0.y); u.y = pk2f(f0.z, f0.w);
  u.z = pk2f(f1.x, f1.y); u.w = pk2f(f1.z, f1.w);
  return __builtin_bit_cast(s8v, u);
}

// tanh-form gelu via exp2 + rcp (scalar — proven)
__device__ __forceinline__ float fast_gelu(float x) {
  float u = x * __builtin_fmaf(0.1029437f, x * x, 2.3022085f);
  float e = exp2f(-u);
  return x * __builtin_amdgcn_rcpf(1.0f + e);
}

// ---------------- helpers (prep) ----------------

// block-wide sum over 1024 threads: wave shfl + 16-partial cross-wave, 3 barriers
__device__ __forceinline__ float block_sum1k(float v, float* redw, float* bcast) {
  const int tid = threadIdx.x;
  #pragma unroll
  for (int m = 32; m > 0; m >>= 1) v += __shfl_xor(v, m, 64);
  if ((tid & 63) == 0) redw[tid >> 6] = v;
  __syncthreads();
  if (tid < 16) {
    float r = redw[tid];
    #pragma unroll
    for (int m = 8; m > 0; m >>= 1) r += __shfl_xor(r, m, 64);
    if (tid == 0) *bcast = r;
  }
  __syncthreads();
  float out = *bcast;
  __syncthreads();
  return out;
}

__device__ __forceinline__ float pe_val(float periods, int freqs, int idx, int c) {
  int f = (c < freqs) ? c : (c - freqs);
  float ang = 3.14159265358979323846f / periods * exp2f((float)f) * ((float)idx - 1.0f);
  return (c < freqs) ? sinf(ang) : cosf(ang);
}

__device__ __forceinline__ float pos_feat(int jj, int dy, int mo, int da, int dw) {
  if (jj < 8)  return pe_val(10.f, 4, dy, jj);
  if (jj < 16) return pe_val(12.f, 4, mo, jj - 8);
  if (jj < 28) return pe_val(31.f, 6, da, jj - 16);
  return pe_val(7.f, 4, dw, jj - 28);
}

// ---------------- kernel W: weights -> bf16 (bias in k=72 row) ----------------
__global__ __launch_bounds__(256) void wconv_kernel(
    const float* __restrict__ wq, const float* __restrict__ wk,
    const float* __restrict__ wvp, const float* __restrict__ wo,
    const float* __restrict__ w1, const float* __restrict__ w2,
    const float* __restrict__ bq, const float* __restrict__ bk,
    const float* __restrict__ bv, const float* __restrict__ bo,
    const float* __restrict__ b1,
    unsigned short* __restrict__ wqkvT, unsigned short* __restrict__ woT,
    unsigned short* __restrict__ w1T, unsigned short* __restrict__ w2P)
{
  const float s18 = 0.23570226039551584f;  // 1/sqrt(18)
  int idx = blockIdx.x * 256 + threadIdx.x;
  if (idx < 23040) {                              // wqkvT [240][96]
    int n = idx / 96, k = idx % 96;
    int mat = n / 80, nc = n % 80;
    const float* w = (mat == 0) ? wq : (mat == 1) ? wk : wvp;
    const float* bb = (mat == 0) ? bq : (mat == 1) ? bk : bv;
    float scale = (mat == 0) ? s18 : 1.0f;
    unsigned short v = 0;
    if (nc < 72) {
      if (k < 72) v = f2b(w[k * 72 + nc] * scale);
      else if (k == 72) v = f2b(bb[nc] * scale);
    }
    wqkvT[idx] = v;
  } else if (idx < 30720) {                       // woT [80][96]
    int i = idx - 23040;
    int n = i / 96, k = i % 96;
    unsigned short v = 0;
    if (n < 72) {
      if (k < 72) v = f2b(wo[k * 72 + n]);
      else if (k == 72) v = f2b(bo[n]);
    }
    woT[i] = v;
  } else if (idx < 141312) {                      // w1T [1152][96]
    int i = idx - 30720;
    int n = i / 96, k = i % 96;
    unsigned short v = 0;
    if (k < 72) v = f2b(w1[(size_t)k * DFF_ + n]);
    else if (k == 72) v = f2b(b1[n]);
    w1T[i] = v;
  } else if (idx < 233472) {                      // w2P [5][36][64][8] (k-permuted)
    int i = idx - 141312;
    int slot = i & 7;
    int lane = (i >> 3) & 63;
    int c    = (i >> 9) % 36;
    int mt5  = i / 18432;
    int la = lane & 15, lg = lane >> 4;
    int kl = (slot < 4) ? (4 * lg + slot) : (16 + 4 * lg + (slot - 4));
    int dff = c * 32 + kl;
    int j = mt5 * 16 + la;
    w2P[i] = (j < 72) ? f2b(w2[(size_t)dff * 72 + j]) : (unsigned short)0;
  }
}

// ---------------- kernel A: preprocess + patch embed — 1024 threads (R13 proven) ----------------
__global__ __launch_bounds__(1024) void prep_kernel(
    const float* __restrict__ history,
    const float* __restrict__ w_nopos, const float* __restrict__ b_nopos,
    const float* __restrict__ w_wpos, const float* __restrict__ b_wpos,
    const float* __restrict__ task_emb,
    const float* __restrict__ w_inp, const float* __restrict__ b_inp,
    const int* __restrict__ ts, const int* __restrict__ target_ts,
    const int* __restrict__ task,
    float* __restrict__ zbuf, float* __restrict__ sbuf, float* __restrict__ d_out)
{
  const int b = blockIdx.x, tid = threadIdx.x;
  __shared__ float hs[SEQ_][73];
  __shared__ float redw[16];
  __shared__ float bcast;
  __shared__ float ps1[8][73], ps2[8][73];
  __shared__ float mu[DM_], rsd[DM_];

  const float* x = history + (size_t)b * T_;

  float xv = (tid < T_) ? x[tid] : 0.0f;
  bool msk1 = (tid < T_) && (xv != 0.0f);
  float sum1 = block_sum1k(msk1 ? xv : 0.0f, redw, &bcast);
  float cnt1 = block_sum1k(msk1 ? 1.0f : 0.0f, redw, &bcast);
  float safe1 = fmaxf(cnt1, 1.0f);
  float mean1 = sum1 / safe1;
  float var1 = block_sum1k(msk1 ? (xv - mean1) * (xv - mean1) : 0.0f, redw, &bcast) / safe1;
  float std1 = (cnt1 > 0.f) ? sqrtf(var1) : 0.0f;
  float mn1  = (cnt1 > 0.f) ? mean1 : 0.0f;
  float hi = mn1 + 2.0f * std1;
  float cl = (tid < T_) ? fminf(fmaxf(xv, 0.0f), hi) : 0.0f;

  bool msk2 = (tid < T_) && (cl != 0.0f);
  float sum2 = block_sum1k(msk2 ? cl : 0.0f, redw, &bcast);
  float cnt2 = block_sum1k(msk2 ? 1.0f : 0.0f, redw, &bcast);
  float safe2 = fmaxf(cnt2, 1.0f);
  float mean2 = sum2 / safe2;
  float var2 = block_sum1k(msk2 ? (cl - mean2) * (cl - mean2) : 0.0f, redw, &bcast) / safe2;
  float std2 = (cnt2 > 0.f) ? sqrtf(var2) : 0.0f;
  float mn2  = (cnt2 > 0.f) ? mean2 : 0.0f;
  const float s = mn2 + std2 + 1e-4f;
  if (tid == 0) { sbuf[b] = s; d_out[B_ + b] = s; }

  const int yr_last = ts[((size_t)b * T_ + (T_ - 1)) * 4 + 0];

  for (int o = tid; o < T_ * DM_; o += 1024) {
    int t = o / DM_, j = o % DM_;
    float h = fminf(fmaxf(x[t] / s, 0.0f), 3.0f);
    float val;
    if (j < EMBED_) {
      val = fmaxf(h * w_nopos[j] + b_nopos[j], 0.0f);
    } else {
      int jj = j - EMBED_;
      float e1 = fmaxf(h * w_wpos[jj] + b_wpos[jj], 0.0f);
      const int* tr = ts + ((size_t)b * T_ + t) * 4;
      int dy = min(max(yr_last - tr[0], 0), 10);
      val = e1 + pos_feat(jj, dy, tr[1], tr[2], tr[3]);
    }
    hs[t][j] = val;
  }
  if (tid < DM_) {
    int j = tid;
    float te = task_emb[task[b] * EMBED_ + (j < EMBED_ ? j : j - EMBED_)];
    if (j < EMBED_) {
      hs[T_][j] = te;
    } else {
      int jj = j - EMBED_;
      const int* qr = target_ts + (size_t)b * 5;
      int yq = min(max(yr_last - qr[0], 0), 10);
      hs[T_][j] = te + pos_feat(jj, yq, qr[1], qr[2], qr[3]);
    }
  }
  __syncthreads();

  if (tid < 576) {
    int d = tid % 72, c = tid / 72;
    int t0 = c * 13, t1 = min(t0 + 13, SEQ_);
    float a1 = 0.f, a2 = 0.f;
    for (int t = t0; t < t1; t++) { float v = hs[t][d]; a1 += v; a2 += v * v; }
    ps1[c][d] = a1; ps2[c][d] = a2;
  }
  __syncthreads();
  if (tid < DM_) {
    float S1 = 0.f, S2 = 0.f;
    #pragma unroll
    for (int c = 0; c < 8; c++) { S1 += ps1[c][tid]; S2 += ps2[c][tid]; }
    float m = S1 * (1.0f / (float)SEQ_);
    float v = fmaxf(S2 * (1.0f / (float)SEQ_) - m * m, 0.f);
    mu[tid] = m; rsd[tid] = rsqrtf(v + 1e-5f);
  }
  __syncthreads();
  for (int o = tid; o < SEQ_ * DM_; o += 1024) {
    int t = o / DM_, d = o % DM_;
    hs[t][d] = (hs[t][d] - mu[d]) * rsd[d];
  }
  __syncthreads();

  for (int o4 = tid; o4 < DM_ * PN_ * (DM_ / 4); o4 += 1024) {
    int jg = o4 % 18, p = (o4 / 18) % PN_, d = o4 / (18 * PN_);
    float4 acc = *(const float4*)&b_inp[jg * 4];
    #pragma unroll
    for (int i = 0; i < PATCH_; i++) {
      int t = p * STRIDE_ + i;
      if (t > T_) t = T_;
      float hv = hs[t][d];
      float4 w4 = *(const float4*)&w_inp[i * DM_ + jg * 4];
      acc.x += hv * w4.x; acc.y += hv * w4.y; acc.z += hv * w4.z; acc.w += hv * w4.w;
    }
    *(float4*)&zbuf[((size_t)(b * DM_ + d) * PN_ + p) * DM_ + jg * 4] = acc;
  }
}

// ---------------- kernel B: FUSED attention + FF block (96 tokens, 384 threads) ----------------
__global__ __launch_bounds__(384) void block_kernel(
    const unsigned short* __restrict__ wqkvT, const unsigned short* __restrict__ woT,
    const unsigned short* __restrict__ w1T, const unsigned short* __restrict__ w2P,
    const float* __restrict__ g1, const float* __restrict__ be1,
    const float* __restrict__ b2,
    const float* __restrict__ g2p, const float* __restrict__ be2,
    const float* __restrict__ gep, const float* __restrict__ beep,
    float* __restrict__ zf)
{
  __shared__ __attribute__((aligned(16))) unsigned short AS[38288];
  float* z1f = (float*)AS;                        // [96][76] f32, overlays qk region post-phase-2

  const int tid = threadIdx.x;
  const int lane = tid & 63, wid = tid >> 6;      // 6 waves
  const int m0 = wid * 16;
  const int la = lane & 15, lg = lane >> 4;
  float* zg = zf + (size_t)blockIdx.x * 8 * PN_ * DM_;   // 96 rows x 72

  const f32x4 Z4 = {0.f, 0.f, 0.f, 0.f};
  const uint4 ZU = {0u, 0u, 0u, 0u};
  const s8v ZF = __builtin_bit_cast(s8v, ZU);

  // ---- zero-init pads ----
  for (int i = tid; i < 768; i += 384) {           // qk e-pads 18..23
    int bofs = i * 24 + 18;
    *(unsigned int*)&AS[bofs] = 0u; *(unsigned int*)&AS[bofs + 2] = 0u;
    *(unsigned int*)&AS[bofs + 4] = 0u;
  }
  for (int i = tid; i < 576; i += 384) {           // vT s-pads 12..15
    int h = i / 144, rem = i % 144, e = rem / 8, r = rem % 8;
    int bofs = VT2_OFF + h * 2448 + e * 136 + r * 16 + 12;
    *(unsigned int*)&AS[bofs] = 0u; *(unsigned int*)&AS[bofs + 2] = 0u;
  }
  for (int i = tid; i < 72; i += 384) {            // vT plane tails 128..135
    int bofs = VT2_OFF + (i / 18) * 2448 + (i % 18) * 136 + 128;
    *(unsigned int*)&AS[bofs] = 0u; *(unsigned int*)&AS[bofs + 2] = 0u;
    *(unsigned int*)&AS[bofs + 4] = 0u; *(unsigned int*)&AS[bofs + 6] = 0u;
  }
  for (int i = tid; i < 1152; i += 384)            // Pt whole
    ((unsigned int*)&AS[PT2_OFF])[i] = 0u;
  for (int i = tid; i < 96; i += 384) {            // o_lds cols 72..79 (72 = 1.0 bias hook)
    int bofs = OL2_OFF + i * 80 + 72;
    *(unsigned int*)&AS[bofs] = 0x3F80u;
    *(unsigned int*)&AS[bofs + 2] = 0u; *(unsigned int*)&AS[bofs + 4] = 0u;
    *(unsigned int*)&AS[bofs + 6] = 0u;
  }
  for (int i = tid; i < 40; i += 384)              // o_lds row 96 (overread guard)
    ((unsigned int*)&AS[OL2_OFF + 96 * 80])[i] = 0u;

  // ---- phase 1: QKV gemm (bias via k=72), q/k head-padded + v transposed ----
  {
    s8v A[3];
    #pragma unroll
    for (int kc = 0; kc < 3; kc++)
      A[kc] = zfrag_any(zg + (m0 + la) * 72, kc * 32 + 8 * lg);

    for (int n0 = 0; n0 < 15; n0++) {
      const int ng = n0 * 16 + la;
      const int mat = ng / 80, nc = ng % 80;
      const int hh = nc / 18, ee = nc % 18;
      f32x4 acc = Z4;
      #pragma unroll
      for (int kc = 0; kc < 3; kc++) {
        s8v Bf = *(const s8v*)&wqkvT[(size_t)ng * KP + kc * 32 + 8 * lg];
        acc = __builtin_amdgcn_mfma_f32_16x16x32_bf16(A[kc], Bf, acc, 0, 0, 0);
      }
      if (nc < 72) {
        if (mat < 2) {
          const int base = ((mat * 4 + hh) * 96) * 24 + ee;
          #pragma unroll
          for (int r = 0; r < 4; r++)
            AS[base + (m0 + 4 * lg + r) * 24] = f2bc(acc[r]);
        } else {
          const int basev = VT2_OFF + hh * 2448 + ee * 136;
          #pragma unroll
          for (int r = 0; r < 4; r++) {
            int tok = m0 + 4 * lg + r;
            AS[basev + (tok / 12) * 16 + tok % 12] = f2bc(acc[r]);
          }
        }
      }
    }
  }
  __syncthreads();

  // ---- phase 2: MFMA attention; 32 (r-group, head) units over 6 waves ----
  {
    const float LOG2E = 1.4426950408889634f;
    const int ptb = PT2_OFF + wid * 384;
    for (int u = wid; u < 32; u += 6) {
      const int rg = u >> 2, h = u & 3;
      const int tokb = rg * 12;
      s8v Aq = *(const s8v*)&AS[((0 * 4 + h) * 96 + tokb + la) * 24 + 8 * lg];
      s8v Bk = *(const s8v*)&AS[((1 * 4 + h) * 96 + tokb + la) * 24 + 8 * lg];
      if (lg == 3) { Aq = ZF; Bk = ZF; }
      f32x4 S = __builtin_amdgcn_mfma_f32_16x16x32_bf16(Aq, Bk, Z4, 0, 0, 0);

      float p[4], rcs[4];
      #pragma unroll
      for (int rr = 0; rr < 4; rr++) {
        float t = (la < 12) ? S[rr] : -3.0e38f;
        float mx = t;
        mx = fmaxf(mx, __shfl_xor(mx, 1, 64));
        mx = fmaxf(mx, __shfl_xor(mx, 2, 64));
        mx = fmaxf(mx, __shfl_xor(mx, 4, 64));
        mx = fmaxf(mx, __shfl_xor(mx, 8, 64));
        float pe = exp2f((t - mx) * LOG2E);
        float sm = pe;
        sm += __shfl_xor(sm, 1, 64);
        sm += __shfl_xor(sm, 2, 64);
        sm += __shfl_xor(sm, 4, 64);
        sm += __shfl_xor(sm, 8, 64);
        p[rr] = pe;
        rcs[rr] = __builtin_amdgcn_rcpf(sm);
      }
      #pragma unroll
      for (int rr = 0; rr < 4; rr++)
        AS[ptb + (4 * lg + rr) * 24 + la] = f2bc(p[rr] * rcs[rr]);

      s8v Ap = *(const s8v*)&AS[ptb + la * 24 + 8 * lg];
      if (lg == 3) Ap = ZF;
      s8v Bv0 = *(const s8v*)&AS[VT2_OFF + h * 2448 + la * 136 + rg * 16 + 8 * lg];
      f32x4 O0 = __builtin_amdgcn_mfma_f32_16x16x32_bf16(Ap, Bv0, Z4, 0, 0, 0);
      s8v Bv1 = *(const s8v*)&AS[VT2_OFF + h * 2448 + (16 + la) * 136 + rg * 16 + 8 * lg];
      f32x4 O1 = __builtin_amdgcn_mfma_f32_16x16x32_bf16(Ap, Bv1, Z4, 0, 0, 0);

      if (lg < 3) {
        #pragma unroll
        for (int rr = 0; rr < 4; rr++) {
          int l = 4 * lg + rr;
          AS[OL2_OFF + (tokb + l) * 80 + h * 18 + la] = f2bc(O0[rr]);
          if (la < 2)
            AS[OL2_OFF + (tokb + l) * 80 + h * 18 + 16 + la] = f2bc(O1[rr]);
        }
      }
    }
  }
  __syncthreads();

  // ---- phase 3: wo gemm + residual + in-register LN1 -> z1f (LDS, stride 76) ----
  {
    s8v A[3];
    #pragma unroll
    for (int kc = 0; kc < 3; kc++)
      A[kc] = *(const s8v*)&AS[OL2_OFF + (m0 + la) * 80 + kc * 32 + 8 * lg];

    f32x4 acc[5];
    #pragma unroll
    for (int n0 = 0; n0 < 5; n0++) {
      acc[n0] = Z4;
      #pragma unroll
      for (int kc = 0; kc < 3; kc++) {
        s8v Bf = *(const s8v*)&woT[(size_t)(n0 * 16 + la) * KP + kc * 32 + 8 * lg];
        acc[n0] = __builtin_amdgcn_mfma_f32_16x16x32_bf16(A[kc], Bf, acc[n0], 0, 0, 0);
      }
    }

    const float inv72 = 1.0f / 72.0f;
    float g1v[5], be1v[5];
    #pragma unroll
    for (int n0 = 0; n0 < 5; n0++) {
      bool ok = (n0 < 4) || (la < 8);
      g1v[n0]  = ok ? g1[n0 * 16 + la] : 0.f;
      be1v[n0] = ok ? be1[n0 * 16 + la] : 0.f;
    }
    #pragma unroll
    for (int r = 0; r < 4; r++) {
      const int t = m0 + 4 * lg + r;
      float vals[5];
      float s1 = 0.f, s2 = 0.f;
      #pragma unroll
      for (int n0 = 0; n0 < 5; n0++) {
        bool ok = (n0 < 4) || (la < 8);
        float x = ok ? (acc[n0][r] + zg[t * 72 + n0 * 16 + la]) : 0.f;
        vals[n0] = x; s1 += x; s2 += x * x;
      }
      s1 += __shfl_xor(s1, 1, 64); s1 += __shfl_xor(s1, 2, 64);
      s1 += __shfl_xor(s1, 4, 64); s1 += __shfl_xor(s1, 8, 64);
      s2 += __shfl_xor(s2, 1, 64); s2 += __shfl_xor(s2, 2, 64);
      s2 += __shfl_xor(s2, 4, 64); s2 += __shfl_xor(s2, 8, 64);
      float mean = s1 * inv72;
      float rs = rsqrtf(fmaxf(s2 * inv72 - mean * mean, 0.f) + 1e-5f);
      #pragma unroll
      for (int n0 = 0; n0 < 5; n0++)
        if ((n0 < 4) || (la < 8))
          z1f[t * 76 + n0 * 16 + la] = (vals[n0] - mean) * rs * g1v[n0] + be1v[n0];
    }
  }
  __syncthreads();

  // ---- phase 4: FF + LN2 + LN3; wave owns 16 tokens (tb2 = wid*16) ----
  {
    const int tb2 = wid * 16;
    // z1 B-fragments from LDS (one-hot bias hook at k=72 synthesized)
    s8v Z2[3];
    #pragma unroll
    for (int kc = 0; kc < 3; kc++)
      Z2[kc] = zfrag_any(z1f + (tb2 + la) * 76, kc * 32 + 8 * lg);

    // acc2 init = b2
    f32x4 acc2[5];
    #pragma unroll
    for (int mt = 0; mt < 5; mt++) {
      f32x4 binit = Z4;
      if (mt < 4 || lg < 2) {
        float bb[4];
        *(float4*)bb = *(const float4*)&b2[mt * 16 + 4 * lg];
        binit[0] = bb[0]; binit[1] = bb[1]; binit[2] = bb[2]; binit[3] = bb[3];
      }
      acc2[mt] = binit;
    }

    const int w1l = la * 96 + 8 * lg;
    const int w2l = lane * 8;

    s8v Af[6], A2r[5];
    #pragma unroll
    for (int mt = 0; mt < 2; mt++)
      #pragma unroll
      for (int kc = 0; kc < 3; kc++)
        Af[mt * 3 + kc] = *(const s8v*)&w1T[mt * 1536 + kc * 32 + w1l];
    #pragma unroll
    for (int mt = 0; mt < 5; mt++)
      A2r[mt] = *(const s8v*)&w2P[mt * 18432 + w2l];

    for (int c = 0; c < 36; c++) {
      const int cn = (c + 1 < 36) ? c + 1 : 35;
      const int n3072 = cn * 3072, n512 = cn * 512;

      f32x4 D1[2];
      D1[0] = Z4; D1[1] = Z4;
      #pragma unroll
      for (int mt = 0; mt < 2; mt++)
        #pragma unroll
        for (int kc = 0; kc < 3; kc++)
          D1[mt] = __builtin_amdgcn_mfma_f32_16x16x32_bf16(Af[mt * 3 + kc], Z2[kc], D1[mt], 0, 0, 0);

      #pragma unroll
      for (int mt = 0; mt < 2; mt++)
        #pragma unroll
        for (int kc = 0; kc < 3; kc++)
          Af[mt * 3 + kc] = *(const s8v*)&w1T[n3072 + mt * 1536 + kc * 32 + w1l];

      uint4 u;
      u.x = pk2f(fast_gelu(D1[0][0]), fast_gelu(D1[0][1]));
      u.y = pk2f(fast_gelu(D1[0][2]), fast_gelu(D1[0][3]));
      u.z = pk2f(fast_gelu(D1[1][0]), fast_gelu(D1[1][1]));
      u.w = pk2f(fast_gelu(D1[1][2]), fast_gelu(D1[1][3]));
      s8v B2 = __builtin_bit_cast(s8v, u);

      #pragma unroll
      for (int mt = 0; mt < 5; mt++)
        acc2[mt] = __builtin_amdgcn_mfma_f32_16x16x32_bf16(A2r[mt], B2, acc2[mt], 0, 0, 0);

      #pragma unroll
      for (int mt = 0; mt < 5; mt++)
        A2r[mt] = *(const s8v*)&w2P[mt * 18432 + n512 + w2l];
    }

    // epilogue: residual (z1 from LDS) + LN2 + LN3 -> zg (global)
    const float inv72 = 1.0f / 72.0f;
    const int t = tb2 + la;
    float v[5][4];
    float s1 = 0.f, s2 = 0.f;
    #pragma unroll
    for (int mt = 0; mt < 5; mt++) {
      if (mt < 4 || lg < 2) {
        float rr[4];
        *(float4*)rr = *(const float4*)&z1f[t * 76 + mt * 16 + 4 * lg];
        #pragma unroll
        for (int r = 0; r < 4; r++) {
          float x = acc2[mt][r] + rr[r];
          v[mt][r] = x; s1 += x; s2 += x * x;
        }
      } else {
        #pragma unroll
        for (int r = 0; r < 4; r++) v[mt][r] = 0.f;
      }
    }
    s1 += __shfl_xor(s1, 16, 64); s1 += __shfl_xor(s1, 32, 64);
    s2 += __shfl_xor(s2, 16, 64); s2 += __shfl_xor(s2, 32, 64);
    float mean = s1 * inv72;
    float rs = rsqrtf(fmaxf(s2 * inv72 - mean * mean, 0.f) + 1e-5f);

    float w[5][4];
    float t1 = 0.f, t2 = 0.f;
    #pragma unroll
    for (int mt = 0; mt < 5; mt++) {
      if (mt < 4 || lg < 2) {
        float gg[4], bb[4];
        *(float4*)gg = *(const float4*)&g2p[mt * 16 + 4 * lg];
        *(float4*)bb = *(const float4*)&be2[mt * 16 + 4 * lg];
        #pragma unroll
        for (int r = 0; r < 4; r++) {
          float x = (v[mt][r] - mean) * rs * gg[r] + bb[r];
          w[mt][r] = x; t1 += x; t2 += x * x;
        }
      } else {
        #pragma unroll
        for (int r = 0; r < 4; r++) w[mt][r] = 0.f;
      }
    }
    t1 += __shfl_xor(t1, 16, 64); t1 += __shfl_xor(t1, 32, 64);
    t2 += __shfl_xor(t2, 16, 64); t2 += __shfl_xor(t2, 32, 64);
    float m2 = t1 * inv72;
    float rs2 = rsqrtf(fmaxf(t2 * inv72 - m2 * m2, 0.f) + 1e-5f);

    #pragma unroll
    for (int mt = 0; mt < 5; mt++) {
      if (mt < 4 || lg < 2) {
        float gg[4], bb[4], o[4];
        *(float4*)gg = *(const float4*)&gep[mt * 16 + 4 * lg];
        *(float4*)bb = *(const float4*)&beep[mt * 16 + 4 * lg];
        #pragma unroll
        for (int r = 0; r < 4; r++)
          o[r] = (w[mt][r] - m2) * rs2 * gg[r] + bb[r];
        *(float4*)&zg[t * 72 + mt * 16 + 4 * lg] = *(const float4*)o;
      }
    }
  }
}

// ---------------- kernel C: output projection + head — 1024 threads ----------------
__global__ __launch_bounds__(1024) void final_kernel(
    const float* __restrict__ zbuf,
    const float* __restrict__ w_outp, const float* __restrict__ b_outp,
    const float* __restrict__ w_head, const float* __restrict__ b_head,
    const float* __restrict__ sbuf, float* __restrict__ d_out)
{
  const int b = blockIdx.x, tid = threadIdx.x;
  const int wave = tid >> 6, lane = tid & 63;
  __shared__ float out0[DM_];
  const float* zb = zbuf + (size_t)b * DM_ * (PN_ * DM_);

  for (int d = wave; d < DM_; d += 16) {
    float acc = 0.f;
    for (int e = lane; e < PN_ * DM_; e += 64) acc += zb[(size_t)d * PN_ * DM_ + e] * w_outp[e];
    #pragma unroll
    for (int m = 32; m > 0; m >>= 1) acc += __shfl_xor(acc, m, 64);
    if (lane == 0) out0[d] = acc + b_outp[0];
  }
  __syncthreads();
  if (tid == 0) {
    float acc = b_head[0];
    for (int d = 0; d < DM_; d++) acc += out0[d] * w_head[d];
    d_out[b] = fmaxf(acc, 0.0f) * sbuf[b];
  }
}

// ---------------- launcher ----------------
extern "C" void kernel_launch(void* const* d_in, const int* in_sizes, int n_in,
                              void* d_out, int out_size, void* d_ws, size_t ws_size,
                              hipStream_t stream) {
  const float* history  = (const float*)d_in[0];
  const float* w_nopos  = (const float*)d_in[1];
  const float* b_nopos  = (const float*)d_in[2];
  const float* w_wpos   = (const float*)d_in[3];
  const float* b_wpos   = (const float*)d_in[4];
  const float* task_emb = (const float*)d_in[5];
  const float* w_inp    = (const float*)d_in[6];
  const float* b_inp    = (const float*)d_in[7];
  const float* wq = (const float*)d_in[8];
  const float* bq = (const float*)d_in[9];
  const float* wk = (const float*)d_in[10];
  const float* bk = (const float*)d_in[11];
  const float* wv = (const float*)d_in[12];
  const float* bv = (const float*)d_in[13];
  const float* wo = (const float*)d_in[14];
  const float* bo = (const float*)d_in[15];
  const float* w_ff1 = (const float*)d_in[16];
  const float* b_ff1 = (const float*)d_in[17];
  const float* w_ff2 = (const float*)d_in[18];
  const float* b_ff2 = (const float*)d_in[19];
  const float* g1  = (const float*)d_in[20];
  const float* be1 = (const float*)d_in[21];
  const float* g2  = (const float*)d_in[22];
  const float* be2 = (const float*)d_in[23];
  const float* ge  = (const float*)d_in[24];
  const float* bee = (const float*)d_in[25];
  const float* w_outp = (const float*)d_in[26];
  const float* b_outp = (const float*)d_in[27];
  const float* w_head = (const float*)d_in[28];
  const float* b_head = (const float*)d_in[29];
  const int* ts        = (const int*)d_in[30];
  const int* target_ts = (const int*)d_in[31];
  const int* task      = (const int*)d_in[32];

  float* out = (float*)d_out;
  char* ws = (char*)d_ws;
  float* zf   = (float*)ws;                                   // 63,700,992
  float* sbuf = (float*)(ws + 63700992);                      // 1,024
  unsigned short* wqkvT = (unsigned short*)(ws + 63702016);   // 46,080
  unsigned short* woT   = (unsigned short*)(ws + 63748096);   // 15,360
  unsigned short* w1T   = (unsigned short*)(ws + 63763456);   // 221,184
  unsigned short* w2P   = (unsigned short*)(ws + 63984640);   // 184,320

  wconv_kernel<<<912, 256, 0, stream>>>(wq, wk, wv, wo, w_ff1, w_ff2,
      bq, bk, bv, bo, b_ff1, wqkvT, woT, w1T, w2P);
  prep_kernel<<<B_, 1024, 0, stream>>>(history, w_nopos, b_nopos, w_wpos, b_wpos,
      task_emb, w_inp, b_inp, ts, target_ts, task, zf, sbuf, out);
  block_kernel<<<2304, 384, 0, stream>>>(wqkvT, woT, w1T, w2P, g1, be1,
      b_ff2, g2, be2, ge, bee, zf);
  final_kernel<<<B_, 1024, 0, stream>>>(zf, w_outp, b_outp, w_head, b_head, sbuf, out);
}

// Round 15
// 388.613 us; speedup vs baseline: 1.1944x; 1.1944x over previous
//
#include <hip/hip_runtime.h>
#include <hip/hip_bf16.h>

#define B_ 256
#define T_ 100
#define EMBED_ 36
#define DM_ 72
#define H_ 4
#define E_ 18
#define PATCH_ 16
#define STRIDE_ 8
#define SEQ_ 101   // T+1
#define PN_ 12
#define DFF_ 1152

#define KP 96      // K padded (72 -> 96)

// attn LDS offsets in u16 units (96-token blocks)
#define VT2_OFF 18432   // after qk [2][4][96][24] = 18,432 u16
#define PT2_OFF 28224   // after vT  (4*2448 = 9,792 u16)
#define OL2_OFF 30528   // after Pt  (6*384 = 2,304 u16)
// o_lds [97][80] = 7,760 u16 -> total 38,288 u16 = 76,576 B

typedef __attribute__((ext_vector_type(8))) short s8v;     // 8 bf16
typedef __attribute__((ext_vector_type(4))) float f32x4;

__device__ __forceinline__ unsigned short f2b(float x) {
  __hip_bfloat16 b = __float2bfloat16(x);
  return __builtin_bit_cast(unsigned short, b);
}
// cheap round-half-up bf16 (<=1 ulp vs RTNE, finite inputs only)
__device__ __forceinline__ unsigned short f2bc(float x) {
  return (unsigned short)((__builtin_bit_cast(unsigned int, x) + 0x8000u) >> 16);
}
__device__ __forceinline__ unsigned int pk2f(float lo, float hi) {
  unsigned int ul = __builtin_bit_cast(unsigned int, lo) + 0x8000u;
  unsigned int uh = __builtin_bit_cast(unsigned int, hi) + 0x8000u;
  return __builtin_amdgcn_perm(uh, ul, 0x07060302u);
}
// bf16 fragment (8 consecutive k) from a global f32 row.
// k0==72 returns the "one-hot" fragment {1,0,...} (bias row selector).
__device__ __forceinline__ s8v zfrag_global(const float* __restrict__ row, int k0) {
  if (k0 >= 72) {
    uint4 z = {0u, 0u, 0u, 0u};
    if (k0 == 72) z.x = 0x3F80u;
    return __builtin_bit_cast(s8v, z);
  }
  float4 f0 = *(const float4*)(row + k0);
  float4 f1 = *(const float4*)(row + k0 + 4);
  uint4 u;
  u.x = pk2f(f0.x, f0.y); u.y = pk2f(f0.z, f0.w);
  u.z = pk2f(f1.x, f1.y); u.w = pk2f(f1.z, f1.w);
  return __builtin_bit_cast(s8v, u);
}

// tanh-form gelu via exp2 + rcp (scalar — R11 proven)
__device__ __forceinline__ float fast_gelu(float x) {
  float u = x * __builtin_fmaf(0.1029437f, x * x, 2.3022085f);
  float e = exp2f(-u);
  return x * __builtin_amdgcn_rcpf(1.0f + e);
}

// ---------------- helpers (prep) ----------------

// block-wide sum over 1024 threads: wave shfl + 16-partial cross-wave, 3 barriers
__device__ __forceinline__ float block_sum1k(float v, float* redw, float* bcast) {
  const int tid = threadIdx.x;
  #pragma unroll
  for (int m = 32; m > 0; m >>= 1) v += __shfl_xor(v, m, 64);
  if ((tid & 63) == 0) redw[tid >> 6] = v;
  __syncthreads();
  if (tid < 16) {
    float r = redw[tid];
    #pragma unroll
    for (int m = 8; m > 0; m >>= 1) r += __shfl_xor(r, m, 64);
    if (tid == 0) *bcast = r;
  }
  __syncthreads();
  float out = *bcast;
  __syncthreads();
  return out;
}

__device__ __forceinline__ float pe_val(float periods, int freqs, int idx, int c) {
  int f = (c < freqs) ? c : (c - freqs);
  float ang = 3.14159265358979323846f / periods * exp2f((float)f) * ((float)idx - 1.0f);
  return (c < freqs) ? sinf(ang) : cosf(ang);
}

__device__ __forceinline__ float pos_feat(int jj, int dy, int mo, int da, int dw) {
  if (jj < 8)  return pe_val(10.f, 4, dy, jj);
  if (jj < 16) return pe_val(12.f, 4, mo, jj - 8);
  if (jj < 28) return pe_val(31.f, 6, da, jj - 16);
  return pe_val(7.f, 4, dw, jj - 28);
}

// ---------------- kernel A: fused wconv (blocks 0..227) + prep (blocks 228..483) ----------------
__global__ __launch_bounds__(1024) void prep_kernel(
    const float* __restrict__ history,
    const float* __restrict__ w_nopos, const float* __restrict__ b_nopos,
    const float* __restrict__ w_wpos, const float* __restrict__ b_wpos,
    const float* __restrict__ task_emb,
    const float* __restrict__ w_inp, const float* __restrict__ b_inp,
    const int* __restrict__ ts, const int* __restrict__ target_ts,
    const int* __restrict__ task,
    const float* __restrict__ wq, const float* __restrict__ wk,
    const float* __restrict__ wvp, const float* __restrict__ wo,
    const float* __restrict__ w1, const float* __restrict__ w2,
    const float* __restrict__ bq, const float* __restrict__ bk,
    const float* __restrict__ bv, const float* __restrict__ bo,
    const float* __restrict__ b1,
    unsigned short* __restrict__ wqkvT, unsigned short* __restrict__ woT,
    unsigned short* __restrict__ w1T, unsigned short* __restrict__ w2P,
    float* __restrict__ zbuf, float* __restrict__ sbuf, float* __restrict__ d_out)
{
  if (blockIdx.x < 228) {
    // ---- weight conversion (bias in k=72 row); 228*1024 = 233472 items exactly ----
    const float s18 = 0.23570226039551584f;  // 1/sqrt(18)
    int idx = blockIdx.x * 1024 + threadIdx.x;
    if (idx < 23040) {                              // wqkvT [240][96]
      int n = idx / 96, k = idx % 96;
      int mat = n / 80, nc = n % 80;
      const float* w = (mat == 0) ? wq : (mat == 1) ? wk : wvp;
      const float* bb = (mat == 0) ? bq : (mat == 1) ? bk : bv;
      float scale = (mat == 0) ? s18 : 1.0f;
      unsigned short v = 0;
      if (nc < 72) {
        if (k < 72) v = f2b(w[k * 72 + nc] * scale);
        else if (k == 72) v = f2b(bb[nc] * scale);
      }
      wqkvT[idx] = v;
    } else if (idx < 30720) {                       // woT [80][96]
      int i = idx - 23040;
      int n = i / 96, k = i % 96;
      unsigned short v = 0;
      if (n < 72) {
        if (k < 72) v = f2b(wo[k * 72 + n]);
        else if (k == 72) v = f2b(bo[n]);
      }
      woT[i] = v;
    } else if (idx < 141312) {                      // w1T [1152][96]
      int i = idx - 30720;
      int n = i / 96, k = i % 96;
      unsigned short v = 0;
      if (k < 72) v = f2b(w1[(size_t)k * DFF_ + n]);
      else if (k == 72) v = f2b(b1[n]);
      w1T[i] = v;
    } else if (idx < 233472) {                      // w2P [5][36][64][8] (k-permuted)
      int i = idx - 141312;
      int slot = i & 7;
      int lane = (i >> 3) & 63;
      int c    = (i >> 9) % 36;
      int mt5  = i / 18432;
      int la = lane & 15, lg = lane >> 4;
      int kl = (slot < 4) ? (4 * lg + slot) : (16 + 4 * lg + (slot - 4));
      int dff = c * 32 + kl;
      int j = mt5 * 16 + la;
      w2P[i] = (j < 72) ? f2b(w2[(size_t)dff * 72 + j]) : (unsigned short)0;
    }
    return;
  }

  // ---- preprocess + patch embed (R13 proven, 1024 threads) ----
  const int b = blockIdx.x - 228, tid = threadIdx.x;
  __shared__ float hs[SEQ_][73];
  __shared__ float redw[16];
  __shared__ float bcast;
  __shared__ float ps1[8][73], ps2[8][73];
  __shared__ float mu[DM_], rsd[DM_];

  const float* x = history + (size_t)b * T_;

  float xv = (tid < T_) ? x[tid] : 0.0f;
  bool msk1 = (tid < T_) && (xv != 0.0f);
  float sum1 = block_sum1k(msk1 ? xv : 0.0f, redw, &bcast);
  float cnt1 = block_sum1k(msk1 ? 1.0f : 0.0f, redw, &bcast);
  float safe1 = fmaxf(cnt1, 1.0f);
  float mean1 = sum1 / safe1;
  float var1 = block_sum1k(msk1 ? (xv - mean1) * (xv - mean1) : 0.0f, redw, &bcast) / safe1;
  float std1 = (cnt1 > 0.f) ? sqrtf(var1) : 0.0f;
  float mn1  = (cnt1 > 0.f) ? mean1 : 0.0f;
  float hi = mn1 + 2.0f * std1;
  float cl = (tid < T_) ? fminf(fmaxf(xv, 0.0f), hi) : 0.0f;

  bool msk2 = (tid < T_) && (cl != 0.0f);
  float sum2 = block_sum1k(msk2 ? cl : 0.0f, redw, &bcast);
  float cnt2 = block_sum1k(msk2 ? 1.0f : 0.0f, redw, &bcast);
  float safe2 = fmaxf(cnt2, 1.0f);
  float mean2 = sum2 / safe2;
  float var2 = block_sum1k(msk2 ? (cl - mean2) * (cl - mean2) : 0.0f, redw, &bcast) / safe2;
  float std2 = (cnt2 > 0.f) ? sqrtf(var2) : 0.0f;
  float mn2  = (cnt2 > 0.f) ? mean2 : 0.0f;
  const float s = mn2 + std2 + 1e-4f;
  if (tid == 0) { sbuf[b] = s; d_out[B_ + b] = s; }

  const int yr_last = ts[((size_t)b * T_ + (T_ - 1)) * 4 + 0];

  for (int o = tid; o < T_ * DM_; o += 1024) {
    int t = o / DM_, j = o % DM_;
    float h = fminf(fmaxf(x[t] / s, 0.0f), 3.0f);
    float val;
    if (j < EMBED_) {
      val = fmaxf(h * w_nopos[j] + b_nopos[j], 0.0f);
    } else {
      int jj = j - EMBED_;
      float e1 = fmaxf(h * w_wpos[jj] + b_wpos[jj], 0.0f);
      const int* tr = ts + ((size_t)b * T_ + t) * 4;
      int dy = min(max(yr_last - tr[0], 0), 10);
      val = e1 + pos_feat(jj, dy, tr[1], tr[2], tr[3]);
    }
    hs[t][j] = val;
  }
  if (tid < DM_) {
    int j = tid;
    float te = task_emb[task[b] * EMBED_ + (j < EMBED_ ? j : j - EMBED_)];
    if (j < EMBED_) {
      hs[T_][j] = te;
    } else {
      int jj = j - EMBED_;
      const int* qr = target_ts + (size_t)b * 5;
      int yq = min(max(yr_last - qr[0], 0), 10);
      hs[T_][j] = te + pos_feat(jj, yq, qr[1], qr[2], qr[3]);
    }
  }
  __syncthreads();

  if (tid < 576) {
    int d = tid % 72, c = tid / 72;
    int t0 = c * 13, t1 = min(t0 + 13, SEQ_);
    float a1 = 0.f, a2 = 0.f;
    for (int t = t0; t < t1; t++) { float v = hs[t][d]; a1 += v; a2 += v * v; }
    ps1[c][d] = a1; ps2[c][d] = a2;
  }
  __syncthreads();
  if (tid < DM_) {
    float S1 = 0.f, S2 = 0.f;
    #pragma unroll
    for (int c = 0; c < 8; c++) { S1 += ps1[c][tid]; S2 += ps2[c][tid]; }
    float m = S1 * (1.0f / (float)SEQ_);
    float v = fmaxf(S2 * (1.0f / (float)SEQ_) - m * m, 0.f);
    mu[tid] = m; rsd[tid] = rsqrtf(v + 1e-5f);
  }
  __syncthreads();
  for (int o = tid; o < SEQ_ * DM_; o += 1024) {
    int t = o / DM_, d = o % DM_;
    hs[t][d] = (hs[t][d] - mu[d]) * rsd[d];
  }
  __syncthreads();

  for (int o4 = tid; o4 < DM_ * PN_ * (DM_ / 4); o4 += 1024) {
    int jg = o4 % 18, p = (o4 / 18) % PN_, d = o4 / (18 * PN_);
    float4 acc = *(const float4*)&b_inp[jg * 4];
    #pragma unroll
    for (int i = 0; i < PATCH_; i++) {
      int t = p * STRIDE_ + i;
      if (t > T_) t = T_;
      float hv = hs[t][d];
      float4 w4 = *(const float4*)&w_inp[i * DM_ + jg * 4];
      acc.x += hv * w4.x; acc.y += hv * w4.y; acc.z += hv * w4.z; acc.w += hv * w4.w;
    }
    *(float4*)&zbuf[((size_t)(b * DM_ + d) * PN_ + p) * DM_ + jg * 4] = acc;
  }
}

// ---------------- kernel B1: QKV + MFMA attention + wo + in-reg LN1 (R13 proven) ----------------
__global__ __launch_bounds__(384) void attn_kernel(
    const unsigned short* __restrict__ wqkvT, const unsigned short* __restrict__ woT,
    const float* __restrict__ g1, const float* __restrict__ be1,
    float* __restrict__ zf)
{
  __shared__ __attribute__((aligned(16))) unsigned short AS[38288];

  const int tid = threadIdx.x;
  const int lane = tid & 63, wid = tid >> 6;      // 6 waves
  const int m0 = wid * 16;
  const int la = lane & 15, lg = lane >> 4;
  float* zg = zf + (size_t)blockIdx.x * 8 * PN_ * DM_;

  const f32x4 Z4 = {0.f, 0.f, 0.f, 0.f};
  const uint4 ZU = {0u, 0u, 0u, 0u};
  const s8v ZF = __builtin_bit_cast(s8v, ZU);

  for (int i = tid; i < 768; i += 384) {
    int bofs = i * 24 + 18;
    *(unsigned int*)&AS[bofs] = 0u; *(unsigned int*)&AS[bofs + 2] = 0u;
    *(unsigned int*)&AS[bofs + 4] = 0u;
  }
  for (int i = tid; i < 576; i += 384) {
    int h = i / 144, rem = i % 144, e = rem / 8, r = rem % 8;
    int bofs = VT2_OFF + h * 2448 + e * 136 + r * 16 + 12;
    *(unsigned int*)&AS[bofs] = 0u; *(unsigned int*)&AS[bofs + 2] = 0u;
  }
  for (int i = tid; i < 72; i += 384) {
    int bofs = VT2_OFF + (i / 18) * 2448 + (i % 18) * 136 + 128;
    *(unsigned int*)&AS[bofs] = 0u; *(unsigned int*)&AS[bofs + 2] = 0u;
    *(unsigned int*)&AS[bofs + 4] = 0u; *(unsigned int*)&AS[bofs + 6] = 0u;
  }
  for (int i = tid; i < 1152; i += 384)
    ((unsigned int*)&AS[PT2_OFF])[i] = 0u;
  for (int i = tid; i < 96; i += 384) {
    int bofs = OL2_OFF + i * 80 + 72;
    *(unsigned int*)&AS[bofs] = 0x3F80u;
    *(unsigned int*)&AS[bofs + 2] = 0u; *(unsigned int*)&AS[bofs + 4] = 0u;
    *(unsigned int*)&AS[bofs + 6] = 0u;
  }
  for (int i = tid; i < 40; i += 384)
    ((unsigned int*)&AS[OL2_OFF + 96 * 80])[i] = 0u;

  {
    s8v A[3];
    #pragma unroll
    for (int kc = 0; kc < 3; kc++)
      A[kc] = zfrag_global(zg + (m0 + la) * 72, kc * 32 + 8 * lg);

    for (int n0 = 0; n0 < 15; n0++) {
      const int ng = n0 * 16 + la;
      const int mat = ng / 80, nc = ng % 80;
      const int hh = nc / 18, ee = nc % 18;
      f32x4 acc = Z4;
      #pragma unroll
      for (int kc = 0; kc < 3; kc++) {
        s8v Bf = *(const s8v*)&wqkvT[(size_t)ng * KP + kc * 32 + 8 * lg];
        acc = __builtin_amdgcn_mfma_f32_16x16x32_bf16(A[kc], Bf, acc, 0, 0, 0);
      }
      if (nc < 72) {
        if (mat < 2) {
          const int base = ((mat * 4 + hh) * 96) * 24 + ee;
          #pragma unroll
          for (int r = 0; r < 4; r++)
            AS[base + (m0 + 4 * lg + r) * 24] = f2bc(acc[r]);
        } else {
          const int basev = VT2_OFF + hh * 2448 + ee * 136;
          #pragma unroll
          for (int r = 0; r < 4; r++) {
            int tok = m0 + 4 * lg + r;
            AS[basev + (tok / 12) * 16 + tok % 12] = f2bc(acc[r]);
          }
        }
      }
    }
  }
  __syncthreads();

  {
    const float LOG2E = 1.4426950408889634f;
    const int ptb = PT2_OFF + wid * 384;
    for (int u = wid; u < 32; u += 6) {
      const int rg = u >> 2, h = u & 3;
      const int tokb = rg * 12;
      s8v Aq = *(const s8v*)&AS[((0 * 4 + h) * 96 + tokb + la) * 24 + 8 * lg];
      s8v Bk = *(const s8v*)&AS[((1 * 4 + h) * 96 + tokb + la) * 24 + 8 * lg];
      if (lg == 3) { Aq = ZF; Bk = ZF; }
      f32x4 S = __builtin_amdgcn_mfma_f32_16x16x32_bf16(Aq, Bk, Z4, 0, 0, 0);

      float p[4], rcs[4];
      #pragma unroll
      for (int rr = 0; rr < 4; rr++) {
        float t = (la < 12) ? S[rr] : -3.0e38f;
        float mx = t;
        mx = fmaxf(mx, __shfl_xor(mx, 1, 64));
        mx = fmaxf(mx, __shfl_xor(mx, 2, 64));
        mx = fmaxf(mx, __shfl_xor(mx, 4, 64));
        mx = fmaxf(mx, __shfl_xor(mx, 8, 64));
        float pe = exp2f((t - mx) * LOG2E);
        float sm = pe;
        sm += __shfl_xor(sm, 1, 64);
        sm += __shfl_xor(sm, 2, 64);
        sm += __shfl_xor(sm, 4, 64);
        sm += __shfl_xor(sm, 8, 64);
        p[rr] = pe;
        rcs[rr] = __builtin_amdgcn_rcpf(sm);
      }
      #pragma unroll
      for (int rr = 0; rr < 4; rr++)
        AS[ptb + (4 * lg + rr) * 24 + la] = f2bc(p[rr] * rcs[rr]);

      s8v Ap = *(const s8v*)&AS[ptb + la * 24 + 8 * lg];
      if (lg == 3) Ap = ZF;
      s8v Bv0 = *(const s8v*)&AS[VT2_OFF + h * 2448 + la * 136 + rg * 16 + 8 * lg];
      f32x4 O0 = __builtin_amdgcn_mfma_f32_16x16x32_bf16(Ap, Bv0, Z4, 0, 0, 0);
      s8v Bv1 = *(const s8v*)&AS[VT2_OFF + h * 2448 + (16 + la) * 136 + rg * 16 + 8 * lg];
      f32x4 O1 = __builtin_amdgcn_mfma_f32_16x16x32_bf16(Ap, Bv1, Z4, 0, 0, 0);

      if (lg < 3) {
        #pragma unroll
        for (int rr = 0; rr < 4; rr++) {
          int l = 4 * lg + rr;
          AS[OL2_OFF + (tokb + l) * 80 + h * 18 + la] = f2bc(O0[rr]);
          if (la < 2)
            AS[OL2_OFF + (tokb + l) * 80 + h * 18 + 16 + la] = f2bc(O1[rr]);
        }
      }
    }
  }
  __syncthreads();

  {
    s8v A[3];
    #pragma unroll
    for (int kc = 0; kc < 3; kc++)
      A[kc] = *(const s8v*)&AS[OL2_OFF + (m0 + la) * 80 + kc * 32 + 8 * lg];

    f32x4 acc[5];
    #pragma unroll
    for (int n0 = 0; n0 < 5; n0++) {
      acc[n0] = Z4;
      #pragma unroll
      for (int kc = 0; kc < 3; kc++) {
        s8v Bf = *(const s8v*)&woT[(size_t)(n0 * 16 + la) * KP + kc * 32 + 8 * lg];
        acc[n0] = __builtin_amdgcn_mfma_f32_16x16x32_bf16(A[kc], Bf, acc[n0], 0, 0, 0);
      }
    }

    const float inv72 = 1.0f / 72.0f;
    float g1v[5], be1v[5];
    #pragma unroll
    for (int n0 = 0; n0 < 5; n0++) {
      bool ok = (n0 < 4) || (la < 8);
      g1v[n0]  = ok ? g1[n0 * 16 + la] : 0.f;
      be1v[n0] = ok ? be1[n0 * 16 + la] : 0.f;
    }
    #pragma unroll
    for (int r = 0; r < 4; r++) {
      const int t = m0 + 4 * lg + r;
      float vals[5];
      float s1 = 0.f, s2 = 0.f;
      #pragma unroll
      for (int n0 = 0; n0 < 5; n0++) {
        bool ok = (n0 < 4) || (la < 8);
        float x = ok ? (acc[n0][r] + zg[t * 72 + n0 * 16 + la]) : 0.f;
        vals[n0] = x; s1 += x; s2 += x * x;
      }
      s1 += __shfl_xor(s1, 1, 64); s1 += __shfl_xor(s1, 2, 64);
      s1 += __shfl_xor(s1, 4, 64); s1 += __shfl_xor(s1, 8, 64);
      s2 += __shfl_xor(s2, 1, 64); s2 += __shfl_xor(s2, 2, 64);
      s2 += __shfl_xor(s2, 4, 64); s2 += __shfl_xor(s2, 8, 64);
      float mean = s1 * inv72;
      float rs = rsqrtf(fmaxf(s2 * inv72 - mean * mean, 0.f) + 1e-5f);
      #pragma unroll
      for (int n0 = 0; n0 < 5; n0++)
        if ((n0 < 4) || (la < 8))
          zg[t * 72 + n0 * 16 + la] = (vals[n0] - mean) * rs * g1v[n0] + be1v[n0];
    }
  }
}

// ---------------- kernel B2: FF + LN2 + LN3 — R11 proven (prefetch + scalar gelu) ----------------
__global__ __launch_bounds__(128) void ff_kernel(
    const unsigned short* __restrict__ w1T, const unsigned short* __restrict__ w2P,
    const float* __restrict__ b2,
    const float* __restrict__ g2p, const float* __restrict__ be2,
    const float* __restrict__ gep, const float* __restrict__ beep,
    float* __restrict__ zf)
{
  const int tid = threadIdx.x;
  const int lane = tid & 63, wid = tid >> 6;      // 2 waves
  const int la = lane & 15, lg = lane >> 4;
  const int tb = wid * 48;
  float* zg = zf + (size_t)blockIdx.x * 96 * DM_;

  const f32x4 Z4 = {0.f, 0.f, 0.f, 0.f};

  s8v Z[3][3];
  #pragma unroll
  for (int nt = 0; nt < 3; nt++)
    #pragma unroll
    for (int kc = 0; kc < 3; kc++)
      Z[nt][kc] = zfrag_global(zg + (tb + nt * 16 + la) * 72, kc * 32 + 8 * lg);

  f32x4 acc2[5][3];
  #pragma unroll
  for (int mt = 0; mt < 5; mt++) {
    f32x4 binit = Z4;
    if (mt < 4 || lg < 2) {
      float bb[4];
      *(float4*)bb = *(const float4*)&b2[mt * 16 + 4 * lg];
      binit[0] = bb[0]; binit[1] = bb[1]; binit[2] = bb[2]; binit[3] = bb[3];
    }
    #pragma unroll
    for (int nt = 0; nt < 3; nt++) acc2[mt][nt] = binit;
  }

  const int w1l = la * 96 + 8 * lg;
  const int w2l = lane * 8;

  s8v Af[6], A2r[5];
  #pragma unroll
  for (int mt = 0; mt < 2; mt++)
    #pragma unroll
    for (int kc = 0; kc < 3; kc++)
      Af[mt * 3 + kc] = *(const s8v*)&w1T[mt * 1536 + kc * 32 + w1l];
  #pragma unroll
  for (int mt = 0; mt < 5; mt++)
    A2r[mt] = *(const s8v*)&w2P[mt * 18432 + w2l];

  for (int c = 0; c < 36; c++) {
    const int cn = (c + 1 < 36) ? c + 1 : 35;
    const int n3072 = cn * 3072, n512 = cn * 512;

    f32x4 D1[2][3];
    #pragma unroll
    for (int mt = 0; mt < 2; mt++)
      #pragma unroll
      for (int nt = 0; nt < 3; nt++) D1[mt][nt] = Z4;
    #pragma unroll
    for (int mt = 0; mt < 2; mt++)
      #pragma unroll
      for (int kc = 0; kc < 3; kc++)
        #pragma unroll
        for (int nt = 0; nt < 3; nt++)
          D1[mt][nt] = __builtin_amdgcn_mfma_f32_16x16x32_bf16(Af[mt * 3 + kc], Z[nt][kc], D1[mt][nt], 0, 0, 0);

    #pragma unroll
    for (int mt = 0; mt < 2; mt++)
      #pragma unroll
      for (int kc = 0; kc < 3; kc++)
        Af[mt * 3 + kc] = *(const s8v*)&w1T[n3072 + mt * 1536 + kc * 32 + w1l];

    s8v B2[3];
    #pragma unroll
    for (int nt = 0; nt < 3; nt++) {
      uint4 u;
      u.x = pk2f(fast_gelu(D1[0][nt][0]), fast_gelu(D1[0][nt][1]));
      u.y = pk2f(fast_gelu(D1[0][nt][2]), fast_gelu(D1[0][nt][3]));
      u.z = pk2f(fast_gelu(D1[1][nt][0]), fast_gelu(D1[1][nt][1]));
      u.w = pk2f(fast_gelu(D1[1][nt][2]), fast_gelu(D1[1][nt][3]));
      B2[nt] = __builtin_bit_cast(s8v, u);
    }

    #pragma unroll
    for (int mt = 0; mt < 5; mt++)
      #pragma unroll
      for (int nt = 0; nt < 3; nt++)
        acc2[mt][nt] = __builtin_amdgcn_mfma_f32_16x16x32_bf16(A2r[mt], B2[nt], acc2[mt][nt], 0, 0, 0);

    #pragma unroll
    for (int mt = 0; mt < 5; mt++)
      A2r[mt] = *(const s8v*)&w2P[mt * 18432 + n512 + w2l];
  }

  const float inv72 = 1.0f / 72.0f;
  #pragma unroll
  for (int nt = 0; nt < 3; nt++) {
    const int t = tb + nt * 16 + la;
    float v[5][4];
    float s1 = 0.f, s2 = 0.f;
    #pragma unroll
    for (int mt = 0; mt < 5; mt++) {
      if (mt < 4 || lg < 2) {
        float rr[4];
        *(float4*)rr = *(const float4*)&zg[t * 72 + mt * 16 + 4 * lg];
        #pragma unroll
        for (int r = 0; r < 4; r++) {
          float x = acc2[mt][nt][r] + rr[r];
          v[mt][r] = x; s1 += x; s2 += x * x;
        }
      } else {
        #pragma unroll
        for (int r = 0; r < 4; r++) v[mt][r] = 0.f;
      }
    }
    s1 += __shfl_xor(s1, 16, 64); s1 += __shfl_xor(s1, 32, 64);
    s2 += __shfl_xor(s2, 16, 64); s2 += __shfl_xor(s2, 32, 64);
    float mean = s1 * inv72;
    float rs = rsqrtf(fmaxf(s2 * inv72 - mean * mean, 0.f) + 1e-5f);

    float w[5][4];
    float t1 = 0.f, t2 = 0.f;
    #pragma unroll
    for (int mt = 0; mt < 5; mt++) {
      if (mt < 4 || lg < 2) {
        float gg[4], bb[4];
        *(float4*)gg = *(const float4*)&g2p[mt * 16 + 4 * lg];
        *(float4*)bb = *(const float4*)&be2[mt * 16 + 4 * lg];
        #pragma unroll
        for (int r = 0; r < 4; r++) {
          float x = (v[mt][r] - mean) * rs * gg[r] + bb[r];
          w[mt][r] = x; t1 += x; t2 += x * x;
        }
      } else {
        #pragma unroll
        for (int r = 0; r < 4; r++) w[mt][r] = 0.f;
      }
    }
    t1 += __shfl_xor(t1, 16, 64); t1 += __shfl_xor(t1, 32, 64);
    t2 += __shfl_xor(t2, 16, 64); t2 += __shfl_xor(t2, 32, 64);
    float m2 = t1 * inv72;
    float rs2 = rsqrtf(fmaxf(t2 * inv72 - m2 * m2, 0.f) + 1e-5f);

    #pragma unroll
    for (int mt = 0; mt < 5; mt++) {
      if (mt < 4 || lg < 2) {
        float gg[4], bb[4], o[4];
        *(float4*)gg = *(const float4*)&gep[mt * 16 + 4 * lg];
        *(float4*)bb = *(const float4*)&beep[mt * 16 + 4 * lg];
        #pragma unroll
        for (int r = 0; r < 4; r++)
          o[r] = (w[mt][r] - m2) * rs2 * gg[r] + bb[r];
        *(float4*)&zg[t * 72 + mt * 16 + 4 * lg] = *(const float4*)o;
      }
    }
  }
}

// ---------------- kernel C: output projection + head — 1024 threads ----------------
__global__ __launch_bounds__(1024) void final_kernel(
    const float* __restrict__ zbuf,
    const float* __restrict__ w_outp, const float* __restrict__ b_outp,
    const float* __restrict__ w_head, const float* __restrict__ b_head,
    const float* __restrict__ sbuf, float* __restrict__ d_out)
{
  const int b = blockIdx.x, tid = threadIdx.x;
  const int wave = tid >> 6, lane = tid & 63;
  __shared__ float out0[DM_];
  const float* zb = zbuf + (size_t)b * DM_ * (PN_ * DM_);

  for (int d = wave; d < DM_; d += 16) {
    float acc = 0.f;
    for (int e = lane; e < PN_ * DM_; e += 64) acc += zb[(size_t)d * PN_ * DM_ + e] * w_outp[e];
    #pragma unroll
    for (int m = 32; m > 0; m >>= 1) acc += __shfl_xor(acc, m, 64);
    if (lane == 0) out0[d] = acc + b_outp[0];
  }
  __syncthreads();
  if (tid == 0) {
    float acc = b_head[0];
    for (int d = 0; d < DM_; d++) acc += out0[d] * w_head[d];
    d_out[b] = fmaxf(acc, 0.0f) * sbuf[b];
  }
}

// ---------------- launcher ----------------
extern "C" void kernel_launch(void* const* d_in, const int* in_sizes, int n_in,
                              void* d_out, int out_size, void* d_ws, size_t ws_size,
                              hipStream_t stream) {
  const float* history  = (const float*)d_in[0];
  const float* w_nopos  = (const float*)d_in[1];
  const float* b_nopos  = (const float*)d_in[2];
  const float* w_wpos   = (const float*)d_in[3];
  const float* b_wpos   = (const float*)d_in[4];
  const float* task_emb = (const float*)d_in[5];
  const float* w_inp    = (const float*)d_in[6];
  const float* b_inp    = (const float*)d_in[7];
  const float* wq = (const float*)d_in[8];
  const float* bq = (const float*)d_in[9];
  const float* wk = (const float*)d_in[10];
  const float* bk = (const float*)d_in[11];
  const float* wv = (const float*)d_in[12];
  const float* bv = (const float*)d_in[13];
  const float* wo = (const float*)d_in[14];
  const float* bo = (const float*)d_in[15];
  const float* w_ff1 = (const float*)d_in[16];
  const float* b_ff1 = (const float*)d_in[17];
  const float* w_ff2 = (const float*)d_in[18];
  const float* b_ff2 = (const float*)d_in[19];
  const float* g1  = (const float*)d_in[20];
  const float* be1 = (const float*)d_in[21];
  const float* g2  = (const float*)d_in[22];
  const float* be2 = (const float*)d_in[23];
  const float* ge  = (const float*)d_in[24];
  const float* bee = (const float*)d_in[25];
  const float* w_outp = (const float*)d_in[26];
  const float* b_outp = (const float*)d_in[27];
  const float* w_head = (const float*)d_in[28];
  const float* b_head = (const float*)d_in[29];
  const int* ts        = (const int*)d_in[30];
  const int* target_ts = (const int*)d_in[31];
  const int* task      = (const int*)d_in[32];

  float* out = (float*)d_out;
  char* ws = (char*)d_ws;
  float* zf   = (float*)ws;                                   // 63,700,992
  float* sbuf = (float*)(ws + 63700992);                      // 1,024
  unsigned short* wqkvT = (unsigned short*)(ws + 63702016);   // 46,080
  unsigned short* woT   = (unsigned short*)(ws + 63748096);   // 15,360
  unsigned short* w1T   = (unsigned short*)(ws + 63763456);   // 221,184
  unsigned short* w2P   = (unsigned short*)(ws + 63984640);   // 184,320

  prep_kernel<<<484, 1024, 0, stream>>>(history, w_nopos, b_nopos, w_wpos, b_wpos,
      task_emb, w_inp, b_inp, ts, target_ts, task,
      wq, wk, wv, wo, w_ff1, w_ff2, bq, bk, bv, bo, b_ff1,
      wqkvT, woT, w1T, w2P, zf, sbuf, out);
  attn_kernel<<<2304, 384, 0, stream>>>(wqkvT, woT, g1, be1, zf);
  ff_kernel<<<2304, 128, 0, stream>>>(w1T, w2P, b_ff2, g2, be2, ge, bee, zf);
  final_kernel<<<B_, 1024, 0, stream>>>(zf, w_outp, b_outp, w_head, b_head, sbuf, out);
}

// Round 16
// 386.708 us; speedup vs baseline: 1.2003x; 1.0049x over previous
//
#include <hip/hip_runtime.h>
#include <hip/hip_bf16.h>

#define B_ 256
#define T_ 100
#define EMBED_ 36
#define DM_ 72
#define H_ 4
#define E_ 18
#define PATCH_ 16
#define STRIDE_ 8
#define SEQ_ 101   // T+1
#define PN_ 12
#define DFF_ 1152

#define KP 96      // K padded (72 -> 96)

// attn LDS offsets in u16 units (96-token blocks)
#define VT2_OFF 18432   // after qk [2][4][96][24] = 18,432 u16
#define PT2_OFF 28224   // after vT  (4*2448 = 9,792 u16)
#define OL2_OFF 30528   // after Pt  (6*384 = 2,304 u16)
// o_lds [97][80] = 7,760 u16 -> total 38,288 u16 = 76,576 B

typedef __attribute__((ext_vector_type(8))) short s8v;     // 8 bf16
typedef __attribute__((ext_vector_type(4))) float f32x4;

__device__ __forceinline__ unsigned short f2b(float x) {
  __hip_bfloat16 b = __float2bfloat16(x);
  return __builtin_bit_cast(unsigned short, b);
}
// cheap round-half-up bf16 (<=1 ulp vs RTNE, finite inputs only)
__device__ __forceinline__ unsigned short f2bc(float x) {
  return (unsigned short)((__builtin_bit_cast(unsigned int, x) + 0x8000u) >> 16);
}
__device__ __forceinline__ unsigned int pk2f(float lo, float hi) {
  unsigned int ul = __builtin_bit_cast(unsigned int, lo) + 0x8000u;
  unsigned int uh = __builtin_bit_cast(unsigned int, hi) + 0x8000u;
  return __builtin_amdgcn_perm(uh, ul, 0x07060302u);
}
// bf16 fragment (8 consecutive k) from a global f32 row.
// k0==72 returns the "one-hot" fragment {1,0,...} (bias row selector).
__device__ __forceinline__ s8v zfrag_global(const float* __restrict__ row, int k0) {
  if (k0 >= 72) {
    uint4 z = {0u, 0u, 0u, 0u};
    if (k0 == 72) z.x = 0x3F80u;
    return __builtin_bit_cast(s8v, z);
  }
  float4 f0 = *(const float4*)(row + k0);
  float4 f1 = *(const float4*)(row + k0 + 4);
  uint4 u;
  u.x = pk2f(f0.x, f0.y); u.y = pk2f(f0.z, f0.w);
  u.z = pk2f(f1.x, f1.y); u.w = pk2f(f1.z, f1.w);
  return __builtin_bit_cast(s8v, u);
}

// tanh-form gelu via exp2 + rcp (scalar — R11 proven)
__device__ __forceinline__ float fast_gelu(float x) {
  float u = x * __builtin_fmaf(0.1029437f, x * x, 2.3022085f);
  float e = exp2f(-u);
  return x * __builtin_amdgcn_rcpf(1.0f + e);
}

// ---------------- helpers (prep) ----------------

// block-wide sum over 1024 threads: wave shfl + 16-partial cross-wave, 3 barriers
__device__ __forceinline__ float block_sum1k(float v, float* redw, float* bcast) {
  const int tid = threadIdx.x;
  #pragma unroll
  for (int m = 32; m > 0; m >>= 1) v += __shfl_xor(v, m, 64);
  if ((tid & 63) == 0) redw[tid >> 6] = v;
  __syncthreads();
  if (tid < 16) {
    float r = redw[tid];
    #pragma unroll
    for (int m = 8; m > 0; m >>= 1) r += __shfl_xor(r, m, 64);
    if (tid == 0) *bcast = r;
  }
  __syncthreads();
  float out = *bcast;
  __syncthreads();
  return out;
}

__device__ __forceinline__ float pe_val(float periods, int freqs, int idx, int c) {
  int f = (c < freqs) ? c : (c - freqs);
  float ang = 3.14159265358979323846f / periods * exp2f((float)f) * ((float)idx - 1.0f);
  return (c < freqs) ? sinf(ang) : cosf(ang);
}

__device__ __forceinline__ float pos_feat(int jj, int dy, int mo, int da, int dw) {
  if (jj < 8)  return pe_val(10.f, 4, dy, jj);
  if (jj < 16) return pe_val(12.f, 4, mo, jj - 8);
  if (jj < 28) return pe_val(31.f, 6, da, jj - 16);
  return pe_val(7.f, 4, dw, jj - 28);
}

// ---------------- kernel A: fused wconv (blocks 0..227) + prep (blocks 228..483) ----------------
__global__ __launch_bounds__(1024) void prep_kernel(
    const float* __restrict__ history,
    const float* __restrict__ w_nopos, const float* __restrict__ b_nopos,
    const float* __restrict__ w_wpos, const float* __restrict__ b_wpos,
    const float* __restrict__ task_emb,
    const float* __restrict__ w_inp, const float* __restrict__ b_inp,
    const int* __restrict__ ts, const int* __restrict__ target_ts,
    const int* __restrict__ task,
    const float* __restrict__ wq, const float* __restrict__ wk,
    const float* __restrict__ wvp, const float* __restrict__ wo,
    const float* __restrict__ w1, const float* __restrict__ w2,
    const float* __restrict__ bq, const float* __restrict__ bk,
    const float* __restrict__ bv, const float* __restrict__ bo,
    const float* __restrict__ b1,
    unsigned short* __restrict__ wqkvT, unsigned short* __restrict__ woT,
    unsigned short* __restrict__ w1T, unsigned short* __restrict__ w2P,
    float* __restrict__ zbuf, float* __restrict__ sbuf, float* __restrict__ d_out)
{
  if (blockIdx.x < 228) {
    // ---- weight conversion (bias in k=72 row); 228*1024 = 233472 items exactly ----
    const float s18 = 0.23570226039551584f;  // 1/sqrt(18)
    int idx = blockIdx.x * 1024 + threadIdx.x;
    if (idx < 23040) {                              // wqkvT [240][96]
      int n = idx / 96, k = idx % 96;
      int mat = n / 80, nc = n % 80;
      const float* w = (mat == 0) ? wq : (mat == 1) ? wk : wvp;
      const float* bb = (mat == 0) ? bq : (mat == 1) ? bk : bv;
      float scale = (mat == 0) ? s18 : 1.0f;
      unsigned short v = 0;
      if (nc < 72) {
        if (k < 72) v = f2b(w[k * 72 + nc] * scale);
        else if (k == 72) v = f2b(bb[nc] * scale);
      }
      wqkvT[idx] = v;
    } else if (idx < 30720) {                       // woT [80][96]
      int i = idx - 23040;
      int n = i / 96, k = i % 96;
      unsigned short v = 0;
      if (n < 72) {
        if (k < 72) v = f2b(wo[k * 72 + n]);
        else if (k == 72) v = f2b(bo[n]);
      }
      woT[i] = v;
    } else if (idx < 141312) {                      // w1T [1152][96]
      int i = idx - 30720;
      int n = i / 96, k = i % 96;
      unsigned short v = 0;
      if (k < 72) v = f2b(w1[(size_t)k * DFF_ + n]);
      else if (k == 72) v = f2b(b1[n]);
      w1T[i] = v;
    } else if (idx < 233472) {                      // w2P [5][36][64][8] (k-permuted)
      int i = idx - 141312;
      int slot = i & 7;
      int lane = (i >> 3) & 63;
      int c    = (i >> 9) % 36;
      int mt5  = i / 18432;
      int la = lane & 15, lg = lane >> 4;
      int kl = (slot < 4) ? (4 * lg + slot) : (16 + 4 * lg + (slot - 4));
      int dff = c * 32 + kl;
      int j = mt5 * 16 + la;
      w2P[i] = (j < 72) ? f2b(w2[(size_t)dff * 72 + j]) : (unsigned short)0;
    }
    return;
  }

  // ---- preprocess + patch embed (R13 proven, 1024 threads) ----
  const int b = blockIdx.x - 228, tid = threadIdx.x;
  __shared__ float hs[SEQ_][73];
  __shared__ float redw[16];
  __shared__ float bcast;
  __shared__ float ps1[8][73], ps2[8][73];
  __shared__ float mu[DM_], rsd[DM_];

  const float* x = history + (size_t)b * T_;

  float xv = (tid < T_) ? x[tid] : 0.0f;
  bool msk1 = (tid < T_) && (xv != 0.0f);
  float sum1 = block_sum1k(msk1 ? xv : 0.0f, redw, &bcast);
  float cnt1 = block_sum1k(msk1 ? 1.0f : 0.0f, redw, &bcast);
  float safe1 = fmaxf(cnt1, 1.0f);
  float mean1 = sum1 / safe1;
  float var1 = block_sum1k(msk1 ? (xv - mean1) * (xv - mean1) : 0.0f, redw, &bcast) / safe1;
  float std1 = (cnt1 > 0.f) ? sqrtf(var1) : 0.0f;
  float mn1  = (cnt1 > 0.f) ? mean1 : 0.0f;
  float hi = mn1 + 2.0f * std1;
  float cl = (tid < T_) ? fminf(fmaxf(xv, 0.0f), hi) : 0.0f;

  bool msk2 = (tid < T_) && (cl != 0.0f);
  float sum2 = block_sum1k(msk2 ? cl : 0.0f, redw, &bcast);
  float cnt2 = block_sum1k(msk2 ? 1.0f : 0.0f, redw, &bcast);
  float safe2 = fmaxf(cnt2, 1.0f);
  float mean2 = sum2 / safe2;
  float var2 = block_sum1k(msk2 ? (cl - mean2) * (cl - mean2) : 0.0f, redw, &bcast) / safe2;
  float std2 = (cnt2 > 0.f) ? sqrtf(var2) : 0.0f;
  float mn2  = (cnt2 > 0.f) ? mean2 : 0.0f;
  const float s = mn2 + std2 + 1e-4f;
  if (tid == 0) { sbuf[b] = s; d_out[B_ + b] = s; }

  const int yr_last = ts[((size_t)b * T_ + (T_ - 1)) * 4 + 0];

  for (int o = tid; o < T_ * DM_; o += 1024) {
    int t = o / DM_, j = o % DM_;
    float h = fminf(fmaxf(x[t] / s, 0.0f), 3.0f);
    float val;
    if (j < EMBED_) {
      val = fmaxf(h * w_nopos[j] + b_nopos[j], 0.0f);
    } else {
      int jj = j - EMBED_;
      float e1 = fmaxf(h * w_wpos[jj] + b_wpos[jj], 0.0f);
      const int* tr = ts + ((size_t)b * T_ + t) * 4;
      int dy = min(max(yr_last - tr[0], 0), 10);
      val = e1 + pos_feat(jj, dy, tr[1], tr[2], tr[3]);
    }
    hs[t][j] = val;
  }
  if (tid < DM_) {
    int j = tid;
    float te = task_emb[task[b] * EMBED_ + (j < EMBED_ ? j : j - EMBED_)];
    if (j < EMBED_) {
      hs[T_][j] = te;
    } else {
      int jj = j - EMBED_;
      const int* qr = target_ts + (size_t)b * 5;
      int yq = min(max(yr_last - qr[0], 0), 10);
      hs[T_][j] = te + pos_feat(jj, yq, qr[1], qr[2], qr[3]);
    }
  }
  __syncthreads();

  if (tid < 576) {
    int d = tid % 72, c = tid / 72;
    int t0 = c * 13, t1 = min(t0 + 13, SEQ_);
    float a1 = 0.f, a2 = 0.f;
    for (int t = t0; t < t1; t++) { float v = hs[t][d]; a1 += v; a2 += v * v; }
    ps1[c][d] = a1; ps2[c][d] = a2;
  }
  __syncthreads();
  if (tid < DM_) {
    float S1 = 0.f, S2 = 0.f;
    #pragma unroll
    for (int c = 0; c < 8; c++) { S1 += ps1[c][tid]; S2 += ps2[c][tid]; }
    float m = S1 * (1.0f / (float)SEQ_);
    float v = fmaxf(S2 * (1.0f / (float)SEQ_) - m * m, 0.f);
    mu[tid] = m; rsd[tid] = rsqrtf(v + 1e-5f);
  }
  __syncthreads();
  for (int o = tid; o < SEQ_ * DM_; o += 1024) {
    int t = o / DM_, d = o % DM_;
    hs[t][d] = (hs[t][d] - mu[d]) * rsd[d];
  }
  __syncthreads();

  for (int o4 = tid; o4 < DM_ * PN_ * (DM_ / 4); o4 += 1024) {
    int jg = o4 % 18, p = (o4 / 18) % PN_, d = o4 / (18 * PN_);
    float4 acc = *(const float4*)&b_inp[jg * 4];
    #pragma unroll
    for (int i = 0; i < PATCH_; i++) {
      int t = p * STRIDE_ + i;
      if (t > T_) t = T_;
      float hv = hs[t][d];
      float4 w4 = *(const float4*)&w_inp[i * DM_ + jg * 4];
      acc.x += hv * w4.x; acc.y += hv * w4.y; acc.z += hv * w4.z; acc.w += hv * w4.w;
    }
    *(float4*)&zbuf[((size_t)(b * DM_ + d) * PN_ + p) * DM_ + jg * 4] = acc;
  }
}

// ---------------- kernel B1: QKV + MFMA attention + wo + in-reg LN1 (R13 proven) ----------------
__global__ __launch_bounds__(384) void attn_kernel(
    const unsigned short* __restrict__ wqkvT, const unsigned short* __restrict__ woT,
    const float* __restrict__ g1, const float* __restrict__ be1,
    float* __restrict__ zf)
{
  __shared__ __attribute__((aligned(16))) unsigned short AS[38288];

  const int tid = threadIdx.x;
  const int lane = tid & 63, wid = tid >> 6;      // 6 waves
  const int m0 = wid * 16;
  const int la = lane & 15, lg = lane >> 4;
  float* zg = zf + (size_t)blockIdx.x * 8 * PN_ * DM_;

  const f32x4 Z4 = {0.f, 0.f, 0.f, 0.f};
  const uint4 ZU = {0u, 0u, 0u, 0u};
  const s8v ZF = __builtin_bit_cast(s8v, ZU);

  for (int i = tid; i < 768; i += 384) {
    int bofs = i * 24 + 18;
    *(unsigned int*)&AS[bofs] = 0u; *(unsigned int*)&AS[bofs + 2] = 0u;
    *(unsigned int*)&AS[bofs + 4] = 0u;
  }
  for (int i = tid; i < 576; i += 384) {
    int h = i / 144, rem = i % 144, e = rem / 8, r = rem % 8;
    int bofs = VT2_OFF + h * 2448 + e * 136 + r * 16 + 12;
    *(unsigned int*)&AS[bofs] = 0u; *(unsigned int*)&AS[bofs + 2] = 0u;
  }
  for (int i = tid; i < 72; i += 384) {
    int bofs = VT2_OFF + (i / 18) * 2448 + (i % 18) * 136 + 128;
    *(unsigned int*)&AS[bofs] = 0u; *(unsigned int*)&AS[bofs + 2] = 0u;
    *(unsigned int*)&AS[bofs + 4] = 0u; *(unsigned int*)&AS[bofs + 6] = 0u;
  }
  for (int i = tid; i < 1152; i += 384)
    ((unsigned int*)&AS[PT2_OFF])[i] = 0u;
  for (int i = tid; i < 96; i += 384) {
    int bofs = OL2_OFF + i * 80 + 72;
    *(unsigned int*)&AS[bofs] = 0x3F80u;
    *(unsigned int*)&AS[bofs + 2] = 0u; *(unsigned int*)&AS[bofs + 4] = 0u;
    *(unsigned int*)&AS[bofs + 6] = 0u;
  }
  for (int i = tid; i < 40; i += 384)
    ((unsigned int*)&AS[OL2_OFF + 96 * 80])[i] = 0u;

  {
    s8v A[3];
    #pragma unroll
    for (int kc = 0; kc < 3; kc++)
      A[kc] = zfrag_global(zg + (m0 + la) * 72, kc * 32 + 8 * lg);

    for (int n0 = 0; n0 < 15; n0++) {
      const int ng = n0 * 16 + la;
      const int mat = ng / 80, nc = ng % 80;
      const int hh = nc / 18, ee = nc % 18;
      f32x4 acc = Z4;
      #pragma unroll
      for (int kc = 0; kc < 3; kc++) {
        s8v Bf = *(const s8v*)&wqkvT[(size_t)ng * KP + kc * 32 + 8 * lg];
        acc = __builtin_amdgcn_mfma_f32_16x16x32_bf16(A[kc], Bf, acc, 0, 0, 0);
      }
      if (nc < 72) {
        if (mat < 2) {
          const int base = ((mat * 4 + hh) * 96) * 24 + ee;
          #pragma unroll
          for (int r = 0; r < 4; r++)
            AS[base + (m0 + 4 * lg + r) * 24] = f2bc(acc[r]);
        } else {
          const int basev = VT2_OFF + hh * 2448 + ee * 136;
          #pragma unroll
          for (int r = 0; r < 4; r++) {
            int tok = m0 + 4 * lg + r;
            AS[basev + (tok / 12) * 16 + tok % 12] = f2bc(acc[r]);
          }
        }
      }
    }
  }
  __syncthreads();

  {
    const float LOG2E = 1.4426950408889634f;
    const int ptb = PT2_OFF + wid * 384;
    for (int u = wid; u < 32; u += 6) {
      const int rg = u >> 2, h = u & 3;
      const int tokb = rg * 12;
      s8v Aq = *(const s8v*)&AS[((0 * 4 + h) * 96 + tokb + la) * 24 + 8 * lg];
      s8v Bk = *(const s8v*)&AS[((1 * 4 + h) * 96 + tokb + la) * 24 + 8 * lg];
      if (lg == 3) { Aq = ZF; Bk = ZF; }
      f32x4 S = __builtin_amdgcn_mfma_f32_16x16x32_bf16(Aq, Bk, Z4, 0, 0, 0);

      float p[4], rcs[4];
      #pragma unroll
      for (int rr = 0; rr < 4; rr++) {
        float t = (la < 12) ? S[rr] : -3.0e38f;
        float mx = t;
        mx = fmaxf(mx, __shfl_xor(mx, 1, 64));
        mx = fmaxf(mx, __shfl_xor(mx, 2, 64));
        mx = fmaxf(mx, __shfl_xor(mx, 4, 64));
        mx = fmaxf(mx, __shfl_xor(mx, 8, 64));
        float pe = exp2f((t - mx) * LOG2E);
        float sm = pe;
        sm += __shfl_xor(sm, 1, 64);
        sm += __shfl_xor(sm, 2, 64);
        sm += __shfl_xor(sm, 4, 64);
        sm += __shfl_xor(sm, 8, 64);
        p[rr] = pe;
        rcs[rr] = __builtin_amdgcn_rcpf(sm);
      }
      #pragma unroll
      for (int rr = 0; rr < 4; rr++)
        AS[ptb + (4 * lg + rr) * 24 + la] = f2bc(p[rr] * rcs[rr]);

      s8v Ap = *(const s8v*)&AS[ptb + la * 24 + 8 * lg];
      if (lg == 3) Ap = ZF;
      s8v Bv0 = *(const s8v*)&AS[VT2_OFF + h * 2448 + la * 136 + rg * 16 + 8 * lg];
      f32x4 O0 = __builtin_amdgcn_mfma_f32_16x16x32_bf16(Ap, Bv0, Z4, 0, 0, 0);
      s8v Bv1 = *(const s8v*)&AS[VT2_OFF + h * 2448 + (16 + la) * 136 + rg * 16 + 8 * lg];
      f32x4 O1 = __builtin_amdgcn_mfma_f32_16x16x32_bf16(Ap, Bv1, Z4, 0, 0, 0);

      if (lg < 3) {
        #pragma unroll
        for (int rr = 0; rr < 4; rr++) {
          int l = 4 * lg + rr;
          AS[OL2_OFF + (tokb + l) * 80 + h * 18 + la] = f2bc(O0[rr]);
          if (la < 2)
            AS[OL2_OFF + (tokb + l) * 80 + h * 18 + 16 + la] = f2bc(O1[rr]);
        }
      }
    }
  }
  __syncthreads();

  {
    s8v A[3];
    #pragma unroll
    for (int kc = 0; kc < 3; kc++)
      A[kc] = *(const s8v*)&AS[OL2_OFF + (m0 + la) * 80 + kc * 32 + 8 * lg];

    f32x4 acc[5];
    #pragma unroll
    for (int n0 = 0; n0 < 5; n0++) {
      acc[n0] = Z4;
      #pragma unroll
      for (int kc = 0; kc < 3; kc++) {
        s8v Bf = *(const s8v*)&woT[(size_t)(n0 * 16 + la) * KP + kc * 32 + 8 * lg];
        acc[n0] = __builtin_amdgcn_mfma_f32_16x16x32_bf16(A[kc], Bf, acc[n0], 0, 0, 0);
      }
    }

    const float inv72 = 1.0f / 72.0f;
    float g1v[5], be1v[5];
    #pragma unroll
    for (int n0 = 0; n0 < 5; n0++) {
      bool ok = (n0 < 4) || (la < 8);
      g1v[n0]  = ok ? g1[n0 * 16 + la] : 0.f;
      be1v[n0] = ok ? be1[n0 * 16 + la] : 0.f;
    }
    #pragma unroll
    for (int r = 0; r < 4; r++) {
      const int t = m0 + 4 * lg + r;
      float vals[5];
      float s1 = 0.f, s2 = 0.f;
      #pragma unroll
      for (int n0 = 0; n0 < 5; n0++) {
        bool ok = (n0 < 4) || (la < 8);
        float x = ok ? (acc[n0][r] + zg[t * 72 + n0 * 16 + la]) : 0.f;
        vals[n0] = x; s1 += x; s2 += x * x;
      }
      s1 += __shfl_xor(s1, 1, 64); s1 += __shfl_xor(s1, 2, 64);
      s1 += __shfl_xor(s1, 4, 64); s1 += __shfl_xor(s1, 8, 64);
      s2 += __shfl_xor(s2, 1, 64); s2 += __shfl_xor(s2, 2, 64);
      s2 += __shfl_xor(s2, 4, 64); s2 += __shfl_xor(s2, 8, 64);
      float mean = s1 * inv72;
      float rs = rsqrtf(fmaxf(s2 * inv72 - mean * mean, 0.f) + 1e-5f);
      #pragma unroll
      for (int n0 = 0; n0 < 5; n0++)
        if ((n0 < 4) || (la < 8))
          zg[t * 72 + n0 * 16 + la] = (vals[n0] - mean) * rs * g1v[n0] + be1v[n0];
    }
  }
}

// ---------------- kernel B2: FF + LN2 + LN3 — depth-2 weight prefetch pipeline ----------------
__global__ __launch_bounds__(128) void ff_kernel(
    const unsigned short* __restrict__ w1T, const unsigned short* __restrict__ w2P,
    const float* __restrict__ b2,
    const float* __restrict__ g2p, const float* __restrict__ be2,
    const float* __restrict__ gep, const float* __restrict__ beep,
    float* __restrict__ zf)
{
  const int tid = threadIdx.x;
  const int lane = tid & 63, wid = tid >> 6;      // 2 waves
  const int la = lane & 15, lg = lane >> 4;
  const int tb = wid * 48;
  float* zg = zf + (size_t)blockIdx.x * 96 * DM_;

  const f32x4 Z4 = {0.f, 0.f, 0.f, 0.f};

  s8v Z[3][3];
  #pragma unroll
  for (int nt = 0; nt < 3; nt++)
    #pragma unroll
    for (int kc = 0; kc < 3; kc++)
      Z[nt][kc] = zfrag_global(zg + (tb + nt * 16 + la) * 72, kc * 32 + 8 * lg);

  f32x4 acc2[5][3];
  #pragma unroll
  for (int mt = 0; mt < 5; mt++) {
    f32x4 binit = Z4;
    if (mt < 4 || lg < 2) {
      float bb[4];
      *(float4*)bb = *(const float4*)&b2[mt * 16 + 4 * lg];
      binit[0] = bb[0]; binit[1] = bb[1]; binit[2] = bb[2]; binit[3] = bb[3];
    }
    #pragma unroll
    for (int nt = 0; nt < 3; nt++) acc2[mt][nt] = binit;
  }

  const int w1l = la * 96 + 8 * lg;
  const int w2l = lane * 8;

  // depth-2 double-buffered weights: A-set (even c), B-set (odd c)
  s8v AfA[6], A2rA[5], AfB[6], A2rB[5];
  #pragma unroll
  for (int mt = 0; mt < 2; mt++)
    #pragma unroll
    for (int kc = 0; kc < 3; kc++) {
      AfA[mt * 3 + kc] = *(const s8v*)&w1T[0 * 3072 + mt * 1536 + kc * 32 + w1l];
      AfB[mt * 3 + kc] = *(const s8v*)&w1T[1 * 3072 + mt * 1536 + kc * 32 + w1l];
    }
  #pragma unroll
  for (int mt = 0; mt < 5; mt++) {
    A2rA[mt] = *(const s8v*)&w2P[mt * 18432 + 0 * 512 + w2l];
    A2rB[mt] = *(const s8v*)&w2P[mt * 18432 + 1 * 512 + w2l];
  }

  #pragma unroll 1
  for (int c = 0; c < 36; c += 2) {
    // ---------- even half: consume A-set, prefetch c+2 into A-set ----------
    {
      const int cn = (c + 2 < 36) ? c + 2 : 35;
      const int n3072 = cn * 3072, n512 = cn * 512;

      f32x4 D1[2][3];
      #pragma unroll
      for (int mt = 0; mt < 2; mt++)
        #pragma unroll
        for (int nt = 0; nt < 3; nt++) D1[mt][nt] = Z4;
      #pragma unroll
      for (int mt = 0; mt < 2; mt++)
        #pragma unroll
        for (int kc = 0; kc < 3; kc++)
          #pragma unroll
          for (int nt = 0; nt < 3; nt++)
            D1[mt][nt] = __builtin_amdgcn_mfma_f32_16x16x32_bf16(AfA[mt * 3 + kc], Z[nt][kc], D1[mt][nt], 0, 0, 0);

      #pragma unroll
      for (int mt = 0; mt < 2; mt++)
        #pragma unroll
        for (int kc = 0; kc < 3; kc++)
          AfA[mt * 3 + kc] = *(const s8v*)&w1T[n3072 + mt * 1536 + kc * 32 + w1l];

      s8v B2[3];
      #pragma unroll
      for (int nt = 0; nt < 3; nt++) {
        uint4 u;
        u.x = pk2f(fast_gelu(D1[0][nt][0]), fast_gelu(D1[0][nt][1]));
        u.y = pk2f(fast_gelu(D1[0][nt][2]), fast_gelu(D1[0][nt][3]));
        u.z = pk2f(fast_gelu(D1[1][nt][0]), fast_gelu(D1[1][nt][1]));
        u.w = pk2f(fast_gelu(D1[1][nt][2]), fast_gelu(D1[1][nt][3]));
        B2[nt] = __builtin_bit_cast(s8v, u);
      }

      #pragma unroll
      for (int mt = 0; mt < 5; mt++)
        #pragma unroll
        for (int nt = 0; nt < 3; nt++)
          acc2[mt][nt] = __builtin_amdgcn_mfma_f32_16x16x32_bf16(A2rA[mt], B2[nt], acc2[mt][nt], 0, 0, 0);

      #pragma unroll
      for (int mt = 0; mt < 5; mt++)
        A2rA[mt] = *(const s8v*)&w2P[mt * 18432 + n512 + w2l];
    }
    // ---------- odd half: consume B-set, prefetch c+3 into B-set ----------
    {
      const int cn = (c + 3 < 36) ? c + 3 : 35;
      const int n3072 = cn * 3072, n512 = cn * 512;

      f32x4 D1[2][3];
      #pragma unroll
      for (int mt = 0; mt < 2; mt++)
        #pragma unroll
        for (int nt = 0; nt < 3; nt++) D1[mt][nt] = Z4;
      #pragma unroll
      for (int mt = 0; mt < 2; mt++)
        #pragma unroll
        for (int kc = 0; kc < 3; kc++)
          #pragma unroll
          for (int nt = 0; nt < 3; nt++)
            D1[mt][nt] = __builtin_amdgcn_mfma_f32_16x16x32_bf16(AfB[mt * 3 + kc], Z[nt][kc], D1[mt][nt], 0, 0, 0);

      #pragma unroll
      for (int mt = 0; mt < 2; mt++)
        #pragma unroll
        for (int kc = 0; kc < 3; kc++)
          AfB[mt * 3 + kc] = *(const s8v*)&w1T[n3072 + mt * 1536 + kc * 32 + w1l];

      s8v B2[3];
      #pragma unroll
      for (int nt = 0; nt < 3; nt++) {
        uint4 u;
        u.x = pk2f(fast_gelu(D1[0][nt][0]), fast_gelu(D1[0][nt][1]));
        u.y = pk2f(fast_gelu(D1[0][nt][2]), fast_gelu(D1[0][nt][3]));
        u.z = pk2f(fast_gelu(D1[1][nt][0]), fast_gelu(D1[1][nt][1]));
        u.w = pk2f(fast_gelu(D1[1][nt][2]), fast_gelu(D1[1][nt][3]));
        B2[nt] = __builtin_bit_cast(s8v, u);
      }

      #pragma unroll
      for (int mt = 0; mt < 5; mt++)
        #pragma unroll
        for (int nt = 0; nt < 3; nt++)
          acc2[mt][nt] = __builtin_amdgcn_mfma_f32_16x16x32_bf16(A2rB[mt], B2[nt], acc2[mt][nt], 0, 0, 0);

      #pragma unroll
      for (int mt = 0; mt < 5; mt++)
        A2rB[mt] = *(const s8v*)&w2P[mt * 18432 + n512 + w2l];
    }
  }

  const float inv72 = 1.0f / 72.0f;
  #pragma unroll
  for (int nt = 0; nt < 3; nt++) {
    const int t = tb + nt * 16 + la;
    float v[5][4];
    float s1 = 0.f, s2 = 0.f;
    #pragma unroll
    for (int mt = 0; mt < 5; mt++) {
      if (mt < 4 || lg < 2) {
        float rr[4];
        *(float4*)rr = *(const float4*)&zg[t * 72 + mt * 16 + 4 * lg];
        #pragma unroll
        for (int r = 0; r < 4; r++) {
          float x = acc2[mt][nt][r] + rr[r];
          v[mt][r] = x; s1 += x; s2 += x * x;
        }
      } else {
        #pragma unroll
        for (int r = 0; r < 4; r++) v[mt][r] = 0.f;
      }
    }
    s1 += __shfl_xor(s1, 16, 64); s1 += __shfl_xor(s1, 32, 64);
    s2 += __shfl_xor(s2, 16, 64); s2 += __shfl_xor(s2, 32, 64);
    float mean = s1 * inv72;
    float rs = rsqrtf(fmaxf(s2 * inv72 - mean * mean, 0.f) + 1e-5f);

    float w[5][4];
    float t1 = 0.f, t2 = 0.f;
    #pragma unroll
    for (int mt = 0; mt < 5; mt++) {
      if (mt < 4 || lg < 2) {
        float gg[4], bb[4];
        *(float4*)gg = *(const float4*)&g2p[mt * 16 + 4 * lg];
        *(float4*)bb = *(const float4*)&be2[mt * 16 + 4 * lg];
        #pragma unroll
        for (int r = 0; r < 4; r++) {
          float x = (v[mt][r] - mean) * rs * gg[r] + bb[r];
          w[mt][r] = x; t1 += x; t2 += x * x;
        }
      } else {
        #pragma unroll
        for (int r = 0; r < 4; r++) w[mt][r] = 0.f;
      }
    }
    t1 += __shfl_xor(t1, 16, 64); t1 += __shfl_xor(t1, 32, 64);
    t2 += __shfl_xor(t2, 16, 64); t2 += __shfl_xor(t2, 32, 64);
    float m2 = t1 * inv72;
    float rs2 = rsqrtf(fmaxf(t2 * inv72 - m2 * m2, 0.f) + 1e-5f);

    #pragma unroll
    for (int mt = 0; mt < 5; mt++) {
      if (mt < 4 || lg < 2) {
        float gg[4], bb[4], o[4];
        *(float4*)gg = *(const float4*)&gep[mt * 16 + 4 * lg];
        *(float4*)bb = *(const float4*)&beep[mt * 16 + 4 * lg];
        #pragma unroll
        for (int r = 0; r < 4; r++)
          o[r] = (w[mt][r] - m2) * rs2 * gg[r] + bb[r];
        *(float4*)&zg[t * 72 + mt * 16 + 4 * lg] = *(const float4*)o;
      }
    }
  }
}

// ---------------- kernel C: output projection + head — 1024 threads ----------------
__global__ __launch_bounds__(1024) void final_kernel(
    const float* __restrict__ zbuf,
    const float* __restrict__ w_outp, const float* __restrict__ b_outp,
    const float* __restrict__ w_head, const float* __restrict__ b_head,
    const float* __restrict__ sbuf, float* __restrict__ d_out)
{
  const int b = blockIdx.x, tid = threadIdx.x;
  const int wave = tid >> 6, lane = tid & 63;
  __shared__ float out0[DM_];
  const float* zb = zbuf + (size_t)b * DM_ * (PN_ * DM_);

  for (int d = wave; d < DM_; d += 16) {
    float acc = 0.f;
    for (int e = lane; e < PN_ * DM_; e += 64) acc += zb[(size_t)d * PN_ * DM_ + e] * w_outp[e];
    #pragma unroll
    for (int m = 32; m > 0; m >>= 1) acc += __shfl_xor(acc, m, 64);
    if (lane == 0) out0[d] = acc + b_outp[0];
  }
  __syncthreads();
  if (tid == 0) {
    float acc = b_head[0];
    for (int d = 0; d < DM_; d++) acc += out0[d] * w_head[d];
    d_out[b] = fmaxf(acc, 0.0f) * sbuf[b];
  }
}

// ---------------- launcher ----------------
extern "C" void kernel_launch(void* const* d_in, const int* in_sizes, int n_in,
                              void* d_out, int out_size, void* d_ws, size_t ws_size,
                              hipStream_t stream) {
  const float* history  = (const float*)d_in[0];
  const float* w_nopos  = (const float*)d_in[1];
  const float* b_nopos  = (const float*)d_in[2];
  const float* w_wpos   = (const float*)d_in[3];
  const float* b_wpos   = (const float*)d_in[4];
  const float* task_emb = (const float*)d_in[5];
  const float* w_inp    = (const float*)d_in[6];
  const float* b_inp    = (const float*)d_in[7];
  const float* wq = (const float*)d_in[8];
  const float* bq = (const float*)d_in[9];
  const float* wk = (const float*)d_in[10];
  const float* bk = (const float*)d_in[11];
  const float* wv = (const float*)d_in[12];
  const float* bv = (const float*)d_in[13];
  const float* wo = (const float*)d_in[14];
  const float* bo = (const float*)d_in[15];
  const float* w_ff1 = (const float*)d_in[16];
  const float* b_ff1 = (const float*)d_in[17];
  const float* w_ff2 = (const float*)d_in[18];
  const float* b_ff2 = (const float*)d_in[19];
  const float* g1  = (const float*)d_in[20];
  const float* be1 = (const float*)d_in[21];
  const float* g2  = (const float*)d_in[22];
  const float* be2 = (const float*)d_in[23];
  const float* ge  = (const float*)d_in[24];
  const float* bee = (const float*)d_in[25];
  const float* w_outp = (const float*)d_in[26];
  const float* b_outp = (const float*)d_in[27];
  const float* w_head = (const float*)d_in[28];
  const float* b_head = (const float*)d_in[29];
  const int* ts        = (const int*)d_in[30];
  const int* target_ts = (const int*)d_in[31];
  const int* task      = (const int*)d_in[32];

  float* out = (float*)d_out;
  char* ws = (char*)d_ws;
  float* zf   = (float*)ws;                                   // 63,700,992
  float* sbuf = (float*)(ws + 63700992);                      // 1,024
  unsigned short* wqkvT = (unsigned short*)(ws + 63702016);   // 46,080
  unsigned short* woT   = (unsigned short*)(ws + 63748096);   // 15,360
  unsigned short* w1T   = (unsigned short*)(ws + 63763456);   // 221,184
  unsigned short* w2P   = (unsigned short*)(ws + 63984640);   // 184,320

  prep_kernel<<<484, 1024, 0, stream>>>(history, w_nopos, b_nopos, w_wpos, b_wpos,
      task_emb, w_inp, b_inp, ts, target_ts, task,
      wq, wk, wv, wo, w_ff1, w_ff2, bq, bk, bv, bo, b_ff1,
      wqkvT, woT, w1T, w2P, zf, sbuf, out);
  attn_kernel<<<2304, 384, 0, stream>>>(wqkvT, woT, g1, be1, zf);
  ff_kernel<<<2304, 128, 0, stream>>>(w1T, w2P, b_ff2, g2, be2, ge, bee, zf);
  final_kernel<<<B_, 1024, 0, stream>>>(zf, w_outp, b_outp, w_head, b_head, sbuf, out);
}

// Round 17
// 378.020 us; speedup vs baseline: 1.2279x; 1.0230x over previous
//
#include <hip/hip_runtime.h>
#include <hip/hip_bf16.h>

#define B_ 256
#define T_ 100
#define EMBED_ 36
#define DM_ 72
#define H_ 4
#define E_ 18
#define PATCH_ 16
#define STRIDE_ 8
#define SEQ_ 101   // T+1
#define PN_ 12
#define DFF_ 1152

#define KP 96      // K padded (72 -> 96)

// attn LDS offsets in u16 units (96-token blocks)
#define VT2_OFF 18432   // after qk [2][4][96][24] = 18,432 u16
#define PT2_OFF 28224   // after vT  (4*2448 = 9,792 u16)
#define OL2_OFF 30528   // after Pt  (6*384 = 2,304 u16)
// o_lds [97][80] = 7,760 u16 -> total 38,288 u16 = 76,576 B

typedef __attribute__((ext_vector_type(8))) short s8v;     // 8 bf16
typedef __attribute__((ext_vector_type(4))) float f32x4;

__device__ __forceinline__ unsigned short f2b(float x) {
  __hip_bfloat16 b = __float2bfloat16(x);
  return __builtin_bit_cast(unsigned short, b);
}
// cheap round-half-up bf16 (<=1 ulp vs RTNE, finite inputs only)
__device__ __forceinline__ unsigned short f2bc(float x) {
  return (unsigned short)((__builtin_bit_cast(unsigned int, x) + 0x8000u) >> 16);
}
__device__ __forceinline__ unsigned int pk2f(float lo, float hi) {
  unsigned int ul = __builtin_bit_cast(unsigned int, lo) + 0x8000u;
  unsigned int uh = __builtin_bit_cast(unsigned int, hi) + 0x8000u;
  return __builtin_amdgcn_perm(uh, ul, 0x07060302u);
}
// bf16 fragment (8 consecutive k) from a global f32 row.
// k0==72 returns the "one-hot" fragment {1,0,...} (bias row selector).
__device__ __forceinline__ s8v zfrag_global(const float* __restrict__ row, int k0) {
  if (k0 >= 72) {
    uint4 z = {0u, 0u, 0u, 0u};
    if (k0 == 72) z.x = 0x3F80u;
    return __builtin_bit_cast(s8v, z);
  }
  float4 f0 = *(const float4*)(row + k0);
  float4 f1 = *(const float4*)(row + k0 + 4);
  uint4 u;
  u.x = pk2f(f0.x, f0.y); u.y = pk2f(f0.z, f0.w);
  u.z = pk2f(f1.x, f1.y); u.w = pk2f(f1.z, f1.w);
  return __builtin_bit_cast(s8v, u);
}

// tanh-form gelu via exp2 + rcp (scalar — R11 proven)
__device__ __forceinline__ float fast_gelu(float x) {
  float u = x * __builtin_fmaf(0.1029437f, x * x, 2.3022085f);
  float e = exp2f(-u);
  return x * __builtin_amdgcn_rcpf(1.0f + e);
}

// ---------------- helpers (prep) ----------------

// block-wide sum over 1024 threads: wave shfl + 16-partial cross-wave, 3 barriers
__device__ __forceinline__ float block_sum1k(float v, float* redw, float* bcast) {
  const int tid = threadIdx.x;
  #pragma unroll
  for (int m = 32; m > 0; m >>= 1) v += __shfl_xor(v, m, 64);
  if ((tid & 63) == 0) redw[tid >> 6] = v;
  __syncthreads();
  if (tid < 16) {
    float r = redw[tid];
    #pragma unroll
    for (int m = 8; m > 0; m >>= 1) r += __shfl_xor(r, m, 64);
    if (tid == 0) *bcast = r;
  }
  __syncthreads();
  float out = *bcast;
  __syncthreads();
  return out;
}

__device__ __forceinline__ float pe_val(float periods, int freqs, int idx, int c) {
  int f = (c < freqs) ? c : (c - freqs);
  float ang = 3.14159265358979323846f / periods * exp2f((float)f) * ((float)idx - 1.0f);
  return (c < freqs) ? sinf(ang) : cosf(ang);
}

__device__ __forceinline__ float pos_feat(int jj, int dy, int mo, int da, int dw) {
  if (jj < 8)  return pe_val(10.f, 4, dy, jj);
  if (jj < 16) return pe_val(12.f, 4, mo, jj - 8);
  if (jj < 28) return pe_val(31.f, 6, da, jj - 16);
  return pe_val(7.f, 4, dw, jj - 28);
}

// ---------------- kernel A: fused wconv (blocks 0..227) + prep (blocks 228..483) ----------------
__global__ __launch_bounds__(1024) void prep_kernel(
    const float* __restrict__ history,
    const float* __restrict__ w_nopos, const float* __restrict__ b_nopos,
    const float* __restrict__ w_wpos, const float* __restrict__ b_wpos,
    const float* __restrict__ task_emb,
    const float* __restrict__ w_inp, const float* __restrict__ b_inp,
    const int* __restrict__ ts, const int* __restrict__ target_ts,
    const int* __restrict__ task,
    const float* __restrict__ wq, const float* __restrict__ wk,
    const float* __restrict__ wvp, const float* __restrict__ wo,
    const float* __restrict__ w1, const float* __restrict__ w2,
    const float* __restrict__ bq, const float* __restrict__ bk,
    const float* __restrict__ bv, const float* __restrict__ bo,
    const float* __restrict__ b1,
    unsigned short* __restrict__ wqkvT, unsigned short* __restrict__ woT,
    unsigned short* __restrict__ w1T, unsigned short* __restrict__ w2P,
    float* __restrict__ zbuf, float* __restrict__ sbuf, float* __restrict__ d_out)
{
  if (blockIdx.x < 228) {
    // ---- weight conversion (bias in k=72 row); 228*1024 = 233472 items exactly ----
    const float s18 = 0.23570226039551584f;  // 1/sqrt(18)
    int idx = blockIdx.x * 1024 + threadIdx.x;
    if (idx < 23040) {                              // wqkvT [240][96]
      int n = idx / 96, k = idx % 96;
      int mat = n / 80, nc = n % 80;
      const float* w = (mat == 0) ? wq : (mat == 1) ? wk : wvp;
      const float* bb = (mat == 0) ? bq : (mat == 1) ? bk : bv;
      float scale = (mat == 0) ? s18 : 1.0f;
      unsigned short v = 0;
      if (nc < 72) {
        if (k < 72) v = f2b(w[k * 72 + nc] * scale);
        else if (k == 72) v = f2b(bb[nc] * scale);
      }
      wqkvT[idx] = v;
    } else if (idx < 30720) {                       // woT [80][96]
      int i = idx - 23040;
      int n = i / 96, k = i % 96;
      unsigned short v = 0;
      if (n < 72) {
        if (k < 72) v = f2b(wo[k * 72 + n]);
        else if (k == 72) v = f2b(bo[n]);
      }
      woT[i] = v;
    } else if (idx < 141312) {                      // w1T [1152][96]
      int i = idx - 30720;
      int n = i / 96, k = i % 96;
      unsigned short v = 0;
      if (k < 72) v = f2b(w1[(size_t)k * DFF_ + n]);
      else if (k == 72) v = f2b(b1[n]);
      w1T[i] = v;
    } else if (idx < 233472) {                      // w2P [5][36][64][8] (k-permuted)
      int i = idx - 141312;
      int slot = i & 7;
      int lane = (i >> 3) & 63;
      int c    = (i >> 9) % 36;
      int mt5  = i / 18432;
      int la = lane & 15, lg = lane >> 4;
      int kl = (slot < 4) ? (4 * lg + slot) : (16 + 4 * lg + (slot - 4));
      int dff = c * 32 + kl;
      int j = mt5 * 16 + la;
      w2P[i] = (j < 72) ? f2b(w2[(size_t)dff * 72 + j]) : (unsigned short)0;
    }
    return;
  }

  // ---- preprocess + patch embed (R13 proven, 1024 threads) ----
  const int b = blockIdx.x - 228, tid = threadIdx.x;
  __shared__ float hs[SEQ_][73];
  __shared__ float redw[16];
  __shared__ float bcast;
  __shared__ float ps1[8][73], ps2[8][73];
  __shared__ float mu[DM_], rsd[DM_];

  const float* x = history + (size_t)b * T_;

  float xv = (tid < T_) ? x[tid] : 0.0f;
  bool msk1 = (tid < T_) && (xv != 0.0f);
  float sum1 = block_sum1k(msk1 ? xv : 0.0f, redw, &bcast);
  float cnt1 = block_sum1k(msk1 ? 1.0f : 0.0f, redw, &bcast);
  float safe1 = fmaxf(cnt1, 1.0f);
  float mean1 = sum1 / safe1;
  float var1 = block_sum1k(msk1 ? (xv - mean1) * (xv - mean1) : 0.0f, redw, &bcast) / safe1;
  float std1 = (cnt1 > 0.f) ? sqrtf(var1) : 0.0f;
  float mn1  = (cnt1 > 0.f) ? mean1 : 0.0f;
  float hi = mn1 + 2.0f * std1;
  float cl = (tid < T_) ? fminf(fmaxf(xv, 0.0f), hi) : 0.0f;

  bool msk2 = (tid < T_) && (cl != 0.0f);
  float sum2 = block_sum1k(msk2 ? cl : 0.0f, redw, &bcast);
  float cnt2 = block_sum1k(msk2 ? 1.0f : 0.0f, redw, &bcast);
  float safe2 = fmaxf(cnt2, 1.0f);
  float mean2 = sum2 / safe2;
  float var2 = block_sum1k(msk2 ? (cl - mean2) * (cl - mean2) : 0.0f, redw, &bcast) / safe2;
  float std2 = (cnt2 > 0.f) ? sqrtf(var2) : 0.0f;
  float mn2  = (cnt2 > 0.f) ? mean2 : 0.0f;
  const float s = mn2 + std2 + 1e-4f;
  if (tid == 0) { sbuf[b] = s; d_out[B_ + b] = s; }

  const int yr_last = ts[((size_t)b * T_ + (T_ - 1)) * 4 + 0];

  for (int o = tid; o < T_ * DM_; o += 1024) {
    int t = o / DM_, j = o % DM_;
    float h = fminf(fmaxf(x[t] / s, 0.0f), 3.0f);
    float val;
    if (j < EMBED_) {
      val = fmaxf(h * w_nopos[j] + b_nopos[j], 0.0f);
    } else {
      int jj = j - EMBED_;
      float e1 = fmaxf(h * w_wpos[jj] + b_wpos[jj], 0.0f);
      const int* tr = ts + ((size_t)b * T_ + t) * 4;
      int dy = min(max(yr_last - tr[0], 0), 10);
      val = e1 + pos_feat(jj, dy, tr[1], tr[2], tr[3]);
    }
    hs[t][j] = val;
  }
  if (tid < DM_) {
    int j = tid;
    float te = task_emb[task[b] * EMBED_ + (j < EMBED_ ? j : j - EMBED_)];
    if (j < EMBED_) {
      hs[T_][j] = te;
    } else {
      int jj = j - EMBED_;
      const int* qr = target_ts + (size_t)b * 5;
      int yq = min(max(yr_last - qr[0], 0), 10);
      hs[T_][j] = te + pos_feat(jj, yq, qr[1], qr[2], qr[3]);
    }
  }
  __syncthreads();

  if (tid < 576) {
    int d = tid % 72, c = tid / 72;
    int t0 = c * 13, t1 = min(t0 + 13, SEQ_);
    float a1 = 0.f, a2 = 0.f;
    for (int t = t0; t < t1; t++) { float v = hs[t][d]; a1 += v; a2 += v * v; }
    ps1[c][d] = a1; ps2[c][d] = a2;
  }
  __syncthreads();
  if (tid < DM_) {
    float S1 = 0.f, S2 = 0.f;
    #pragma unroll
    for (int c = 0; c < 8; c++) { S1 += ps1[c][tid]; S2 += ps2[c][tid]; }
    float m = S1 * (1.0f / (float)SEQ_);
    float v = fmaxf(S2 * (1.0f / (float)SEQ_) - m * m, 0.f);
    mu[tid] = m; rsd[tid] = rsqrtf(v + 1e-5f);
  }
  __syncthreads();
  for (int o = tid; o < SEQ_ * DM_; o += 1024) {
    int t = o / DM_, d = o % DM_;
    hs[t][d] = (hs[t][d] - mu[d]) * rsd[d];
  }
  __syncthreads();

  for (int o4 = tid; o4 < DM_ * PN_ * (DM_ / 4); o4 += 1024) {
    int jg = o4 % 18, p = (o4 / 18) % PN_, d = o4 / (18 * PN_);
    float4 acc = *(const float4*)&b_inp[jg * 4];
    #pragma unroll
    for (int i = 0; i < PATCH_; i++) {
      int t = p * STRIDE_ + i;
      if (t > T_) t = T_;
      float hv = hs[t][d];
      float4 w4 = *(const float4*)&w_inp[i * DM_ + jg * 4];
      acc.x += hv * w4.x; acc.y += hv * w4.y; acc.z += hv * w4.z; acc.w += hv * w4.w;
    }
    *(float4*)&zbuf[((size_t)(b * DM_ + d) * PN_ + p) * DM_ + jg * 4] = acc;
  }
}

// ---------------- kernel B1: QKV + MFMA attention + wo + in-reg LN1 (R13 proven) ----------------
__global__ __launch_bounds__(384) void attn_kernel(
    const unsigned short* __restrict__ wqkvT, const unsigned short* __restrict__ woT,
    const float* __restrict__ g1, const float* __restrict__ be1,
    float* __restrict__ zf)
{
  __shared__ __attribute__((aligned(16))) unsigned short AS[38288];

  const int tid = threadIdx.x;
  const int lane = tid & 63, wid = tid >> 6;      // 6 waves
  const int m0 = wid * 16;
  const int la = lane & 15, lg = lane >> 4;
  float* zg = zf + (size_t)blockIdx.x * 8 * PN_ * DM_;

  const f32x4 Z4 = {0.f, 0.f, 0.f, 0.f};
  const uint4 ZU = {0u, 0u, 0u, 0u};
  const s8v ZF = __builtin_bit_cast(s8v, ZU);

  for (int i = tid; i < 768; i += 384) {
    int bofs = i * 24 + 18;
    *(unsigned int*)&AS[bofs] = 0u; *(unsigned int*)&AS[bofs + 2] = 0u;
    *(unsigned int*)&AS[bofs + 4] = 0u;
  }
  for (int i = tid; i < 576; i += 384) {
    int h = i / 144, rem = i % 144, e = rem / 8, r = rem % 8;
    int bofs = VT2_OFF + h * 2448 + e * 136 + r * 16 + 12;
    *(unsigned int*)&AS[bofs] = 0u; *(unsigned int*)&AS[bofs + 2] = 0u;
  }
  for (int i = tid; i < 72; i += 384) {
    int bofs = VT2_OFF + (i / 18) * 2448 + (i % 18) * 136 + 128;
    *(unsigned int*)&AS[bofs] = 0u; *(unsigned int*)&AS[bofs + 2] = 0u;
    *(unsigned int*)&AS[bofs + 4] = 0u; *(unsigned int*)&AS[bofs + 6] = 0u;
  }
  for (int i = tid; i < 1152; i += 384)
    ((unsigned int*)&AS[PT2_OFF])[i] = 0u;
  for (int i = tid; i < 96; i += 384) {
    int bofs = OL2_OFF + i * 80 + 72;
    *(unsigned int*)&AS[bofs] = 0x3F80u;
    *(unsigned int*)&AS[bofs + 2] = 0u; *(unsigned int*)&AS[bofs + 4] = 0u;
    *(unsigned int*)&AS[bofs + 6] = 0u;
  }
  for (int i = tid; i < 40; i += 384)
    ((unsigned int*)&AS[OL2_OFF + 96 * 80])[i] = 0u;

  {
    s8v A[3];
    #pragma unroll
    for (int kc = 0; kc < 3; kc++)
      A[kc] = zfrag_global(zg + (m0 + la) * 72, kc * 32 + 8 * lg);

    for (int n0 = 0; n0 < 15; n0++) {
      const int ng = n0 * 16 + la;
      const int mat = ng / 80, nc = ng % 80;
      const int hh = nc / 18, ee = nc % 18;
      f32x4 acc = Z4;
      #pragma unroll
      for (int kc = 0; kc < 3; kc++) {
        s8v Bf = *(const s8v*)&wqkvT[(size_t)ng * KP + kc * 32 + 8 * lg];
        acc = __builtin_amdgcn_mfma_f32_16x16x32_bf16(A[kc], Bf, acc, 0, 0, 0);
      }
      if (nc < 72) {
        if (mat < 2) {
          const int base = ((mat * 4 + hh) * 96) * 24 + ee;
          #pragma unroll
          for (int r = 0; r < 4; r++)
            AS[base + (m0 + 4 * lg + r) * 24] = f2bc(acc[r]);
        } else {
          const int basev = VT2_OFF + hh * 2448 + ee * 136;
          #pragma unroll
          for (int r = 0; r < 4; r++) {
            int tok = m0 + 4 * lg + r;
            AS[basev + (tok / 12) * 16 + tok % 12] = f2bc(acc[r]);
          }
        }
      }
    }
  }
  __syncthreads();

  {
    const float LOG2E = 1.4426950408889634f;
    const int ptb = PT2_OFF + wid * 384;
    for (int u = wid; u < 32; u += 6) {
      const int rg = u >> 2, h = u & 3;
      const int tokb = rg * 12;
      s8v Aq = *(const s8v*)&AS[((0 * 4 + h) * 96 + tokb + la) * 24 + 8 * lg];
      s8v Bk = *(const s8v*)&AS[((1 * 4 + h) * 96 + tokb + la) * 24 + 8 * lg];
      if (lg == 3) { Aq = ZF; Bk = ZF; }
      f32x4 S = __builtin_amdgcn_mfma_f32_16x16x32_bf16(Aq, Bk, Z4, 0, 0, 0);

      float p[4], rcs[4];
      #pragma unroll
      for (int rr = 0; rr < 4; rr++) {
        float t = (la < 12) ? S[rr] : -3.0e38f;
        float mx = t;
        mx = fmaxf(mx, __shfl_xor(mx, 1, 64));
        mx = fmaxf(mx, __shfl_xor(mx, 2, 64));
        mx = fmaxf(mx, __shfl_xor(mx, 4, 64));
        mx = fmaxf(mx, __shfl_xor(mx, 8, 64));
        float pe = exp2f((t - mx) * LOG2E);
        float sm = pe;
        sm += __shfl_xor(sm, 1, 64);
        sm += __shfl_xor(sm, 2, 64);
        sm += __shfl_xor(sm, 4, 64);
        sm += __shfl_xor(sm, 8, 64);
        p[rr] = pe;
        rcs[rr] = __builtin_amdgcn_rcpf(sm);
      }
      #pragma unroll
      for (int rr = 0; rr < 4; rr++)
        AS[ptb + (4 * lg + rr) * 24 + la] = f2bc(p[rr] * rcs[rr]);

      s8v Ap = *(const s8v*)&AS[ptb + la * 24 + 8 * lg];
      if (lg == 3) Ap = ZF;
      s8v Bv0 = *(const s8v*)&AS[VT2_OFF + h * 2448 + la * 136 + rg * 16 + 8 * lg];
      f32x4 O0 = __builtin_amdgcn_mfma_f32_16x16x32_bf16(Ap, Bv0, Z4, 0, 0, 0);
      s8v Bv1 = *(const s8v*)&AS[VT2_OFF + h * 2448 + (16 + la) * 136 + rg * 16 + 8 * lg];
      f32x4 O1 = __builtin_amdgcn_mfma_f32_16x16x32_bf16(Ap, Bv1, Z4, 0, 0, 0);

      if (lg < 3) {
        #pragma unroll
        for (int rr = 0; rr < 4; rr++) {
          int l = 4 * lg + rr;
          AS[OL2_OFF + (tokb + l) * 80 + h * 18 + la] = f2bc(O0[rr]);
          if (la < 2)
            AS[OL2_OFF + (tokb + l) * 80 + h * 18 + 16 + la] = f2bc(O1[rr]);
        }
      }
    }
  }
  __syncthreads();

  {
    s8v A[3];
    #pragma unroll
    for (int kc = 0; kc < 3; kc++)
      A[kc] = *(const s8v*)&AS[OL2_OFF + (m0 + la) * 80 + kc * 32 + 8 * lg];

    f32x4 acc[5];
    #pragma unroll
    for (int n0 = 0; n0 < 5; n0++) {
      acc[n0] = Z4;
      #pragma unroll
      for (int kc = 0; kc < 3; kc++) {
        s8v Bf = *(const s8v*)&woT[(size_t)(n0 * 16 + la) * KP + kc * 32 + 8 * lg];
        acc[n0] = __builtin_amdgcn_mfma_f32_16x16x32_bf16(A[kc], Bf, acc[n0], 0, 0, 0);
      }
    }

    const float inv72 = 1.0f / 72.0f;
    float g1v[5], be1v[5];
    #pragma unroll
    for (int n0 = 0; n0 < 5; n0++) {
      bool ok = (n0 < 4) || (la < 8);
      g1v[n0]  = ok ? g1[n0 * 16 + la] : 0.f;
      be1v[n0] = ok ? be1[n0 * 16 + la] : 0.f;
    }
    #pragma unroll
    for (int r = 0; r < 4; r++) {
      const int t = m0 + 4 * lg + r;
      float vals[5];
      float s1 = 0.f, s2 = 0.f;
      #pragma unroll
      for (int n0 = 0; n0 < 5; n0++) {
        bool ok = (n0 < 4) || (la < 8);
        float x = ok ? (acc[n0][r] + zg[t * 72 + n0 * 16 + la]) : 0.f;
        vals[n0] = x; s1 += x; s2 += x * x;
      }
      s1 += __shfl_xor(s1, 1, 64); s1 += __shfl_xor(s1, 2, 64);
      s1 += __shfl_xor(s1, 4, 64); s1 += __shfl_xor(s1, 8, 64);
      s2 += __shfl_xor(s2, 1, 64); s2 += __shfl_xor(s2, 2, 64);
      s2 += __shfl_xor(s2, 4, 64); s2 += __shfl_xor(s2, 8, 64);
      float mean = s1 * inv72;
      float rs = rsqrtf(fmaxf(s2 * inv72 - mean * mean, 0.f) + 1e-5f);
      #pragma unroll
      for (int n0 = 0; n0 < 5; n0++)
        if ((n0 < 4) || (la < 8))
          zg[t * 72 + n0 * 16 + la] = (vals[n0] - mean) * rs * g1v[n0] + be1v[n0];
    }
  }
}

// ---------------- kernel B2: FF + LN2 + LN3 — split-K over dff (4 waves) ----------------
// waves 0,1: tokens 0-47 / 48-95, c in [0,18); waves 2,3: same tokens, c in [18,36).
// acc2 of waves 2,3 combined into 0,1 via LDS; epilogue on waves 0,1.
__global__ __launch_bounds__(256) void ff_kernel(
    const unsigned short* __restrict__ w1T, const unsigned short* __restrict__ w2P,
    const float* __restrict__ b2,
    const float* __restrict__ g2p, const float* __restrict__ be2,
    const float* __restrict__ gep, const float* __restrict__ beep,
    float* __restrict__ zf)
{
  __shared__ float accl[128 * 61];                // stride 61 floats: conflict-free scalar access

  const int tid = threadIdx.x;
  const int lane = tid & 63, wid = tid >> 6;      // 4 waves
  const int wsub = wid & 1;                       // token half
  const int ch   = wid >> 1;                      // c half
  const int la = lane & 15, lg = lane >> 4;
  const int tb = wsub * 48;
  float* zg = zf + (size_t)blockIdx.x * 96 * DM_;

  const f32x4 Z4 = {0.f, 0.f, 0.f, 0.f};

  s8v Z[3][3];
  #pragma unroll
  for (int nt = 0; nt < 3; nt++)
    #pragma unroll
    for (int kc = 0; kc < 3; kc++)
      Z[nt][kc] = zfrag_global(zg + (tb + nt * 16 + la) * 72, kc * 32 + 8 * lg);

  // acc2 init: b2 only on ch==0 (avoid double-count)
  f32x4 acc2[5][3];
  #pragma unroll
  for (int mt = 0; mt < 5; mt++) {
    f32x4 binit = Z4;
    if (ch == 0 && (mt < 4 || lg < 2)) {
      float bb[4];
      *(float4*)bb = *(const float4*)&b2[mt * 16 + 4 * lg];
      binit[0] = bb[0]; binit[1] = bb[1]; binit[2] = bb[2]; binit[3] = bb[3];
    }
    #pragma unroll
    for (int nt = 0; nt < 3; nt++) acc2[mt][nt] = binit;
  }

  const int w1l = la * 96 + 8 * lg;
  const int w2l = lane * 8;
  const int c0 = ch * 18, c1 = c0 + 18;

  // depth-1 prefetch within the half (R11 proven)
  s8v Af[6], A2r[5];
  #pragma unroll
  for (int mt = 0; mt < 2; mt++)
    #pragma unroll
    for (int kc = 0; kc < 3; kc++)
      Af[mt * 3 + kc] = *(const s8v*)&w1T[c0 * 3072 + mt * 1536 + kc * 32 + w1l];
  #pragma unroll
  for (int mt = 0; mt < 5; mt++)
    A2r[mt] = *(const s8v*)&w2P[mt * 18432 + c0 * 512 + w2l];

  for (int c = c0; c < c1; c++) {
    const int cn = (c + 1 < c1) ? c + 1 : c1 - 1;
    const int n3072 = cn * 3072, n512 = cn * 512;

    f32x4 D1[2][3];
    #pragma unroll
    for (int mt = 0; mt < 2; mt++)
      #pragma unroll
      for (int nt = 0; nt < 3; nt++) D1[mt][nt] = Z4;
    #pragma unroll
    for (int mt = 0; mt < 2; mt++)
      #pragma unroll
      for (int kc = 0; kc < 3; kc++)
        #pragma unroll
        for (int nt = 0; nt < 3; nt++)
          D1[mt][nt] = __builtin_amdgcn_mfma_f32_16x16x32_bf16(Af[mt * 3 + kc], Z[nt][kc], D1[mt][nt], 0, 0, 0);

    #pragma unroll
    for (int mt = 0; mt < 2; mt++)
      #pragma unroll
      for (int kc = 0; kc < 3; kc++)
        Af[mt * 3 + kc] = *(const s8v*)&w1T[n3072 + mt * 1536 + kc * 32 + w1l];

    s8v B2[3];
    #pragma unroll
    for (int nt = 0; nt < 3; nt++) {
      uint4 u;
      u.x = pk2f(fast_gelu(D1[0][nt][0]), fast_gelu(D1[0][nt][1]));
      u.y = pk2f(fast_gelu(D1[0][nt][2]), fast_gelu(D1[0][nt][3]));
      u.z = pk2f(fast_gelu(D1[1][nt][0]), fast_gelu(D1[1][nt][1]));
      u.w = pk2f(fast_gelu(D1[1][nt][2]), fast_gelu(D1[1][nt][3]));
      B2[nt] = __builtin_bit_cast(s8v, u);
    }

    #pragma unroll
    for (int mt = 0; mt < 5; mt++)
      #pragma unroll
      for (int nt = 0; nt < 3; nt++)
        acc2[mt][nt] = __builtin_amdgcn_mfma_f32_16x16x32_bf16(A2r[mt], B2[nt], acc2[mt][nt], 0, 0, 0);

    #pragma unroll
    for (int mt = 0; mt < 5; mt++)
      A2r[mt] = *(const s8v*)&w2P[mt * 18432 + n512 + w2l];
  }

  // ---- split-K combine: waves 2,3 spill acc2; waves 0,1 accumulate ----
  if (wid >= 2) {
    float* dst = &accl[(tid - 128) * 61];
    #pragma unroll
    for (int mt = 0; mt < 5; mt++)
      #pragma unroll
      for (int nt = 0; nt < 3; nt++)
        #pragma unroll
        for (int r = 0; r < 4; r++)
          dst[(mt * 3 + nt) * 4 + r] = acc2[mt][nt][r];
  }
  __syncthreads();
  if (wid < 2) {
    const float* src = &accl[tid * 61];
    #pragma unroll
    for (int mt = 0; mt < 5; mt++)
      #pragma unroll
      for (int nt = 0; nt < 3; nt++)
        #pragma unroll
        for (int r = 0; r < 4; r++)
          acc2[mt][nt][r] += src[(mt * 3 + nt) * 4 + r];

    // epilogue: residual (b2 already in acc2), LN2, LN3 fused in-register
    const float inv72 = 1.0f / 72.0f;
    #pragma unroll
    for (int nt = 0; nt < 3; nt++) {
      const int t = tb + nt * 16 + la;
      float v[5][4];
      float s1 = 0.f, s2 = 0.f;
      #pragma unroll
      for (int mt = 0; mt < 5; mt++) {
        if (mt < 4 || lg < 2) {
          float rr[4];
          *(float4*)rr = *(const float4*)&zg[t * 72 + mt * 16 + 4 * lg];
          #pragma unroll
          for (int r = 0; r < 4; r++) {
            float x = acc2[mt][nt][r] + rr[r];
            v[mt][r] = x; s1 += x; s2 += x * x;
          }
        } else {
          #pragma unroll
          for (int r = 0; r < 4; r++) v[mt][r] = 0.f;
        }
      }
      s1 += __shfl_xor(s1, 16, 64); s1 += __shfl_xor(s1, 32, 64);
      s2 += __shfl_xor(s2, 16, 64); s2 += __shfl_xor(s2, 32, 64);
      float mean = s1 * inv72;
      float rs = rsqrtf(fmaxf(s2 * inv72 - mean * mean, 0.f) + 1e-5f);

      float w[5][4];
      float t1 = 0.f, t2 = 0.f;
      #pragma unroll
      for (int mt = 0; mt < 5; mt++) {
        if (mt < 4 || lg < 2) {
          float gg[4], bb[4];
          *(float4*)gg = *(const float4*)&g2p[mt * 16 + 4 * lg];
          *(float4*)bb = *(const float4*)&be2[mt * 16 + 4 * lg];
          #pragma unroll
          for (int r = 0; r < 4; r++) {
            float x = (v[mt][r] - mean) * rs * gg[r] + bb[r];
            w[mt][r] = x; t1 += x; t2 += x * x;
          }
        } else {
          #pragma unroll
          for (int r = 0; r < 4; r++) w[mt][r] = 0.f;
        }
      }
      t1 += __shfl_xor(t1, 16, 64); t1 += __shfl_xor(t1, 32, 64);
      t2 += __shfl_xor(t2, 16, 64); t2 += __shfl_xor(t2, 32, 64);
      float m2 = t1 * inv72;
      float rs2 = rsqrtf(fmaxf(t2 * inv72 - m2 * m2, 0.f) + 1e-5f);

      #pragma unroll
      for (int mt = 0; mt < 5; mt++) {
        if (mt < 4 || lg < 2) {
          float gg[4], bb[4], o[4];
          *(float4*)gg = *(const float4*)&gep[mt * 16 + 4 * lg];
          *(float4*)bb = *(const float4*)&beep[mt * 16 + 4 * lg];
          #pragma unroll
          for (int r = 0; r < 4; r++)
            o[r] = (w[mt][r] - m2) * rs2 * gg[r] + bb[r];
          *(float4*)&zg[t * 72 + mt * 16 + 4 * lg] = *(const float4*)o;
        }
      }
    }
  }
}

// ---------------- kernel C: output projection + head — 1024 threads ----------------
__global__ __launch_bounds__(1024) void final_kernel(
    const float* __restrict__ zbuf,
    const float* __restrict__ w_outp, const float* __restrict__ b_outp,
    const float* __restrict__ w_head, const float* __restrict__ b_head,
    const float* __restrict__ sbuf, float* __restrict__ d_out)
{
  const int b = blockIdx.x, tid = threadIdx.x;
  const int wave = tid >> 6, lane = tid & 63;
  __shared__ float out0[DM_];
  const float* zb = zbuf + (size_t)b * DM_ * (PN_ * DM_);

  for (int d = wave; d < DM_; d += 16) {
    float acc = 0.f;
    for (int e = lane; e < PN_ * DM_; e += 64) acc += zb[(size_t)d * PN_ * DM_ + e] * w_outp[e];
    #pragma unroll
    for (int m = 32; m > 0; m >>= 1) acc += __shfl_xor(acc, m, 64);
    if (lane == 0) out0[d] = acc + b_outp[0];
  }
  __syncthreads();
  if (tid == 0) {
    float acc = b_head[0];
    for (int d = 0; d < DM_; d++) acc += out0[d] * w_head[d];
    d_out[b] = fmaxf(acc, 0.0f) * sbuf[b];
  }
}

// ---------------- launcher ----------------
extern "C" void kernel_launch(void* const* d_in, const int* in_sizes, int n_in,
                              void* d_out, int out_size, void* d_ws, size_t ws_size,
                              hipStream_t stream) {
  const float* history  = (const float*)d_in[0];
  const float* w_nopos  = (const float*)d_in[1];
  const float* b_nopos  = (const float*)d_in[2];
  const float* w_wpos   = (const float*)d_in[3];
  const float* b_wpos   = (const float*)d_in[4];
  const float* task_emb = (const float*)d_in[5];
  const float* w_inp    = (const float*)d_in[6];
  const float* b_inp    = (const float*)d_in[7];
  const float* wq = (const float*)d_in[8];
  const float* bq = (const float*)d_in[9];
  const float* wk = (const float*)d_in[10];
  const float* bk = (const float*)d_in[11];
  const float* wv = (const float*)d_in[12];
  const float* bv = (const float*)d_in[13];
  const float* wo = (const float*)d_in[14];
  const float* bo = (const float*)d_in[15];
  const float* w_ff1 = (const float*)d_in[16];
  const float* b_ff1 = (const float*)d_in[17];
  const float* w_ff2 = (const float*)d_in[18];
  const float* b_ff2 = (const float*)d_in[19];
  const float* g1  = (const float*)d_in[20];
  const float* be1 = (const float*)d_in[21];
  const float* g2  = (const float*)d_in[22];
  const float* be2 = (const float*)d_in[23];
  const float* ge  = (const float*)d_in[24];
  const float* bee = (const float*)d_in[25];
  const float* w_outp = (const float*)d_in[26];
  const float* b_outp = (const float*)d_in[27];
  const float* w_head = (const float*)d_in[28];
  const float* b_head = (const float*)d_in[29];
  const int* ts        = (const int*)d_in[30];
  const int* target_ts = (const int*)d_in[31];
  const int* task      = (const int*)d_in[32];

  float* out = (float*)d_out;
  char* ws = (char*)d_ws;
  float* zf   = (float*)ws;                                   // 63,700,992
  float* sbuf = (float*)(ws + 63700992);                      // 1,024
  unsigned short* wqkvT = (unsigned short*)(ws + 63702016);   // 46,080
  unsigned short* woT   = (unsigned short*)(ws + 63748096);   // 15,360
  unsigned short* w1T   = (unsigned short*)(ws + 63763456);   // 221,184
  unsigned short* w2P   = (unsigned short*)(ws + 63984640);   // 184,320

  prep_kernel<<<484, 1024, 0, stream>>>(history, w_nopos, b_nopos, w_wpos, b_wpos,
      task_emb, w_inp, b_inp, ts, target_ts, task,
      wq, wk, wv, wo, w_ff1, w_ff2, bq, bk, bv, bo, b_ff1,
      wqkvT, woT, w1T, w2P, zf, sbuf, out);
  attn_kernel<<<2304, 384, 0, stream>>>(wqkvT, woT, g1, be1, zf);
  ff_kernel<<<2304, 256, 0, stream>>>(w1T, w2P, b_ff2, g2, be2, ge, bee, zf);
  final_kernel<<<B_, 1024, 0, stream>>>(zf, w_outp, b_outp, w_head, b_head, sbuf, out);
}